// Round 1
// baseline (46890.103 us; speedup 1.0000x reference)
//
#include <hip/hip_runtime.h>
#include <hip/hip_cooperative_groups.h>
#include <math.h>

namespace cg = cooperative_groups;

#define SEQ   512
#define BATCH 128
#define INP   512
#define HID   1024
#define G4    4096   // 4*HID
#define NOUT  4

typedef short bf16x8 __attribute__((ext_vector_type(8)));
typedef float f32x4  __attribute__((ext_vector_type(4)));

__device__ __forceinline__ unsigned short f2bf(float x) {  // RNE fp32->bf16
  unsigned int u = __float_as_uint(x);
  unsigned int r = (u + 0x7FFFu + ((u >> 16) & 1u)) >> 16;
  return (unsigned short)r;
}
__device__ __forceinline__ float bf2f(unsigned short h) {
  return __uint_as_float(((unsigned int)h) << 16);
}

// ---------------------------------------------------------------------------
// prepack W_hh [4096][1024] fp32 into fragment-linear bf16 hi/lo:
// out index ((bk4*32 + kstep)*64 + L)*8 + i  holds W[row][k] with
//   m = L&15, q = L>>4, g = m&3, jj = m>>2, row = g*HID + bk4*4 + jj,
//   k = kstep*32 + q*8 + i.
// Slab bk4 (4 j's) is contiguous (16384 shorts = 32 KB per buffer).
// ---------------------------------------------------------------------------
__global__ void prepack_w(const float* __restrict__ W,
                          unsigned short* __restrict__ Whi,
                          unsigned short* __restrict__ Wlo) {
  int T = blockIdx.x * blockDim.x + threadIdx.x;   // < 256*32*64
  int L = T & 63;
  int kstep = (T >> 6) & 31;
  int bk = T >> 11;
  int m = L & 15, q = L >> 4;
  int row = (m & 3) * HID + bk * 4 + (m >> 2);
  int k = kstep * 32 + q * 8;
  const float* src = W + (size_t)row * HID + k;
  unsigned short hi[8], lo[8];
#pragma unroll
  for (int i = 0; i < 8; i++) {
    float x = src[i];
    unsigned short h = f2bf(x);
    hi[i] = h;
    lo[i] = f2bf(x - bf2f(h));
  }
  size_t o = (size_t)T * 8;
#pragma unroll
  for (int i = 0; i < 8; i++) { Whi[o + i] = hi[i]; Wlo[o + i] = lo[i]; }
}

// ---------------------------------------------------------------------------
// init: h0 [B][H] fp32 -> h_hi/h_lo [B][H] bf16 (same layout);
//       c0 [B][H] -> cT [H][B] fp32 (transposed).
// ---------------------------------------------------------------------------
__global__ void init_state(const float* __restrict__ h0, const float* __restrict__ c0,
                           unsigned short* __restrict__ hhi, unsigned short* __restrict__ hlo,
                           float* __restrict__ cT) {
  int idx = blockIdx.x * blockDim.x + threadIdx.x;  // < BATCH*HID
  int b = idx >> 10;          // h layout [b][j]
  int j = idx & (HID - 1);
  float x = h0[idx];
  unsigned short h = f2bf(x);
  hhi[idx] = h;
  hlo[idx] = f2bf(x - bf2f(h));
  cT[j * BATCH + b] = c0[idx];
}

// ---------------------------------------------------------------------------
// transpose a chunk of inputs: in [nrows][INP] -> xt [INP][nrows]
// ---------------------------------------------------------------------------
__global__ void transpose_in(const float* __restrict__ in, float* __restrict__ xt,
                             int nrows) {
  __shared__ float s[32][33];
  int tx = threadIdx.x & 31, ty = threadIdx.x >> 5;  // ty < 8
  int n0 = blockIdx.x * 32, i0 = blockIdx.y * 32;
#pragma unroll
  for (int r = 0; r < 4; r++) {
    int n = n0 + ty + 8 * r;
    s[ty + 8 * r][tx] = in[(size_t)n * INP + i0 + tx];
  }
  __syncthreads();
#pragma unroll
  for (int r = 0; r < 4; r++) {
    int i = i0 + ty + 8 * r;
    xt[(size_t)i * nrows + n0 + tx] = s[tx][ty + 8 * r];
  }
}

// ---------------------------------------------------------------------------
// gemm_xproj: C[4096][N] = W_ih[4096][512] @ Xt[512][N] + (b_ih + b_hh)
// (proven kernel, unchanged this round; MFMA conversion is the next lever)
// ---------------------------------------------------------------------------
__global__ __launch_bounds__(256, 3)
void gemm_xproj(const float* __restrict__ A, const float* __restrict__ Bm,
                const float* __restrict__ b_ih, const float* __restrict__ b_hh,
                float* __restrict__ C, int N) {
  __shared__ float As[32][128];
  __shared__ float Bs[32][128];
  int t = threadIdx.x;
  int g0 = blockIdx.x * 128;
  int n0 = blockIdx.y * 128;
  int mg = (t >> 4) * 8, nn = (t & 15) * 8;
  float acc[8][8] = {};
  for (int k0 = 0; k0 < INP; k0 += 32) {
#pragma unroll
    for (int r = 0; r < 4; r++) {
      int idx = t + 256 * r;
      int g = idx >> 3, i4 = idx & 7;
      float4 v = *(const float4*)&A[(size_t)(g0 + g) * INP + k0 + 4 * i4];
      As[4 * i4 + 0][g] = v.x; As[4 * i4 + 1][g] = v.y;
      As[4 * i4 + 2][g] = v.z; As[4 * i4 + 3][g] = v.w;
    }
#pragma unroll
    for (int r = 0; r < 4; r++) {
      int idx = t + 256 * r;
      int kk = idx >> 5, n4 = idx & 31;
      *(float4*)&Bs[kk][4 * n4] = *(const float4*)&Bm[(size_t)(k0 + kk) * N + n0 + 4 * n4];
    }
    __syncthreads();
#pragma unroll 4
    for (int kk = 0; kk < 32; kk++) {
      float4 a0 = *(const float4*)&As[kk][mg];
      float4 a1 = *(const float4*)&As[kk][mg + 4];
      float4 bb0 = *(const float4*)&Bs[kk][nn];
      float4 bb1 = *(const float4*)&Bs[kk][nn + 4];
      float av[8] = {a0.x, a0.y, a0.z, a0.w, a1.x, a1.y, a1.z, a1.w};
      float bv[8] = {bb0.x, bb0.y, bb0.z, bb0.w, bb1.x, bb1.y, bb1.z, bb1.w};
#pragma unroll
      for (int i2 = 0; i2 < 8; i2++)
#pragma unroll
        for (int j2 = 0; j2 < 8; j2++)
          acc[i2][j2] = fmaf(av[i2], bv[j2], acc[i2][j2]);
    }
    __syncthreads();
  }
#pragma unroll
  for (int i2 = 0; i2 < 8; i2++) {
    int g = g0 + mg + i2;
    float bias = b_ih[g] + b_hh[g];
#pragma unroll
    for (int j2 = 0; j2 < 8; j2++) {
      C[(size_t)g * N + n0 + nn + j2] = acc[i2][j2] + bias;
    }
  }
}

// ---------------------------------------------------------------------------
// lstm_seq (R8): PERSISTENT cooperative kernel — CT timesteps in ONE launch,
// grid.sync() between steps (ping-pong h buffers -> one sync per step).
//
// Re-tiled vs R7 to halve per-step L2 ingest:
//   256 blocks x 256 thr (4 waves). Block bk: jblk = bk>>1 owns j =
//   8*jblk..8*jblk+7 (TWO prepack slabs, 32 W rows); bhalf = bk&1 owns
//   batches b = 64*bhalf..+63. Wave w owns b-tile 16w..16w+15; each lane
//   computes 2 M-tiles (j = 8jblk+q and +4), all 4 gates, batch b.
//
// Wins vs R7 (576 KB/block/step L2-ingest-bound + 512 launches):
//   * W (128 KB hi+lo) staged in LDS ONCE per chunk, not per step
//   * h read per block: 512 KB -> 256 KB (64 batches not 128)
//   * c lives in registers across the whole chunk (no cT traffic)
//   * zero per-step launch overhead; cost is grid.sync (~1-2 us)
// Per-step per-CU ingest: ~268 KB vs 576 KB; aggregate 68 MB vs 147 MB.
//
// Coherence: h writes are cross-XCD; __threadfence() (agent-scope wb/inv)
// before AND after grid.sync() makes step t's h[dst] visible to step t+1's
// readers and invalidates stale L1/L2 lines. W is in LDS -> unaffected.
// ---------------------------------------------------------------------------
__global__ __launch_bounds__(256)
void lstm_seq(const unsigned short* __restrict__ Whi,
              const unsigned short* __restrict__ Wlo,
              const float* __restrict__ XP, int N, int CT, int step0,
              unsigned short* __restrict__ h0hi, unsigned short* __restrict__ h0lo,
              unsigned short* __restrict__ h1hi, unsigned short* __restrict__ h1lo,
              float* __restrict__ cT) {
  __shared__ bf16x8 Wlds[8192];   // 128 KB: [0..4095]=hi (2 slabs), [4096..8191]=lo

  cg::grid_group grid = cg::this_grid();

  int bk = blockIdx.x;            // 0..255
  int jblk = bk >> 1;             // 0..127 -> j0 = 8*jblk
  int bh2 = bk & 1;               // batch half
  int t = threadIdx.x;            // 0..255
  int w = t >> 6;                 // wave 0..3
  int L = t & 63;
  int n = L & 15, q = L >> 4;
  int b = bh2 * 64 + w * 16 + n;
  int j0 = jblk * 8 + q;          // mt=0 row; mt=1 is j0+4

  // ---- stage BOTH W slabs (bk4 = 2*jblk, 2*jblk+1) into LDS once ----
  {
    float4* ldsf = (float4*)Wlds;
    const float4* s1 = (const float4*)(Whi + (size_t)jblk * 32768);
    const float4* s2 = (const float4*)(Wlo + (size_t)jblk * 32768);
#pragma unroll
    for (int i = 0; i < 16; i++) ldsf[t + 256 * i] = s1[t + 256 * i];
#pragma unroll
    for (int i = 0; i < 16; i++) ldsf[4096 + t + 256 * i] = s2[t + 256 * i];
  }

  int ci0 = j0 * BATCH + b;
  int ci1 = (j0 + 4) * BATCH + b;
  float cc0 = cT[ci0];            // c stays in registers for the whole chunk
  float cc1 = cT[ci1];

  size_t hoff = (size_t)b * HID + q * 8;
  size_t o0 = (size_t)b * HID + j0;

  __syncthreads();

  for (int tt = 0; tt < CT; tt++) {
    int gs = step0 + tt;
    int odd = gs & 1;
    const unsigned short* Bh = (odd ? h1hi : h0hi) + hoff;
    const unsigned short* Bl = (odd ? h1lo : h0lo) + hoff;
    unsigned short* dhi = odd ? h0hi : h1hi;
    unsigned short* dlo = odd ? h0lo : h1lo;
    const float* xpc = XP + (size_t)tt * BATCH;

    // xp prefetch (independent of h) — overlaps the MFMA loop
    float xpv0[4], xpv1[4];
#pragma unroll
    for (int g = 0; g < 4; g++) {
      xpv0[g] = xpc[(size_t)(g * HID + j0) * N + b];
      xpv1[g] = xpc[(size_t)(g * HID + j0 + 4) * N + b];
    }

    f32x4 acc0 = {0.f, 0.f, 0.f, 0.f};
    f32x4 acc1 = {0.f, 0.f, 0.f, 0.f};
#pragma unroll 4
    for (int ks = 0; ks < 32; ks++) {
      bf16x8 bhv = *(const bf16x8*)(Bh + ks * 32);
      bf16x8 blv = *(const bf16x8*)(Bl + ks * 32);
      bf16x8 ah0 = Wlds[ks * 64 + L];
      bf16x8 ah1 = Wlds[2048 + ks * 64 + L];
      bf16x8 al0 = Wlds[4096 + ks * 64 + L];
      bf16x8 al1 = Wlds[6144 + ks * 64 + L];
      acc0 = __builtin_amdgcn_mfma_f32_16x16x32_bf16(ah0, bhv, acc0, 0, 0, 0);
      acc1 = __builtin_amdgcn_mfma_f32_16x16x32_bf16(ah1, bhv, acc1, 0, 0, 0);
      acc0 = __builtin_amdgcn_mfma_f32_16x16x32_bf16(ah0, blv, acc0, 0, 0, 0);
      acc1 = __builtin_amdgcn_mfma_f32_16x16x32_bf16(ah1, blv, acc1, 0, 0, 0);
      acc0 = __builtin_amdgcn_mfma_f32_16x16x32_bf16(al0, bhv, acc0, 0, 0, 0);
      acc1 = __builtin_amdgcn_mfma_f32_16x16x32_bf16(al1, bhv, acc1, 0, 0, 0);
    }

    {   // cell update, M-tile 0 (j = j0)
      float i_ = 1.f / (1.f + expf(-(acc0[0] + xpv0[0])));
      float f_ = 1.f / (1.f + expf(-(acc0[1] + xpv0[1])));
      float g_ = tanhf(acc0[2] + xpv0[2]);
      float o_ = 1.f / (1.f + expf(-(acc0[3] + xpv0[3])));
      cc0 = f_ * cc0 + i_ * g_;
      float hn = o_ * tanhf(cc0);
      unsigned short hh = f2bf(hn);
      dhi[o0] = hh;
      dlo[o0] = f2bf(hn - bf2f(hh));
    }
    {   // cell update, M-tile 1 (j = j0+4)
      float i_ = 1.f / (1.f + expf(-(acc1[0] + xpv1[0])));
      float f_ = 1.f / (1.f + expf(-(acc1[1] + xpv1[1])));
      float g_ = tanhf(acc1[2] + xpv1[2]);
      float o_ = 1.f / (1.f + expf(-(acc1[3] + xpv1[3])));
      cc1 = f_ * cc1 + i_ * g_;
      float hn = o_ * tanhf(cc1);
      unsigned short hh = f2bf(hn);
      dhi[o0 + 4] = hh;
      dlo[o0 + 4] = f2bf(hn - bf2f(hh));
    }

    __threadfence();   // release: h[dst] writes -> coherence point (cross-XCD)
    grid.sync();
    __threadfence();   // acquire: invalidate stale L1/L2 before next h read
  }

  cT[ci0] = cc0;
  cT[ci1] = cc1;
}

// ---------------------------------------------------------------------------
// decode + softmax over batch dim (axis 0); h from hi+lo bf16 [B][H]
// ---------------------------------------------------------------------------
__global__ void decode_softmax(const unsigned short* __restrict__ hhi,
                               const unsigned short* __restrict__ hlo,
                               const float* __restrict__ Wd,
                               const float* __restrict__ bd, float* __restrict__ out) {
  __shared__ float lg[NOUT][BATCH];
  __shared__ float mx[NOUT], sm[NOUT];
  int t = threadIdx.x;  // 512 threads
  int b = t >> 2, o = t & 3;
  float s = bd[o];
  for (int j = 0; j < HID; j++) {
    float hv = bf2f(hhi[(size_t)b * HID + j]) + bf2f(hlo[(size_t)b * HID + j]);
    s += hv * Wd[o * HID + j];
  }
  lg[o][b] = s;
  __syncthreads();
  if (t < NOUT) {
    float m = -1e30f;
    for (int b2 = 0; b2 < BATCH; b2++) m = fmaxf(m, lg[t][b2]);
    float ss = 0.f;
    for (int b2 = 0; b2 < BATCH; b2++) ss += expf(lg[t][b2] - m);
    mx[t] = m; sm[t] = ss;
  }
  __syncthreads();
  out[b * NOUT + o] = expf(lg[o][b] - mx[o]) / sm[o];
}

// ---------------------------------------------------------------------------
extern "C" void kernel_launch(void* const* d_in, const int* in_sizes, int n_in,
                              void* d_out, int out_size, void* d_ws, size_t ws_size,
                              hipStream_t stream) {
  const float* inputs = (const float*)d_in[0];
  const float* h0     = (const float*)d_in[1];
  const float* c0     = (const float*)d_in[2];
  const float* W_ih   = (const float*)d_in[3];
  const float* W_hh   = (const float*)d_in[4];
  const float* b_ih   = (const float*)d_in[5];
  const float* b_hh   = (const float*)d_in[6];
  const float* W_dec  = (const float*)d_in[7];
  const float* b_dec  = (const float*)d_in[8];
  float* out = (float*)d_out;

  char* w = (char*)d_ws;
  unsigned short* Whi = (unsigned short*)w;  w += (size_t)G4 * HID * 2;
  unsigned short* Wlo = (unsigned short*)w;  w += (size_t)G4 * HID * 2;
  unsigned short* hhi[2], *hlo[2];
  hhi[0] = (unsigned short*)w;  w += (size_t)BATCH * HID * 2;
  hhi[1] = (unsigned short*)w;  w += (size_t)BATCH * HID * 2;
  hlo[0] = (unsigned short*)w;  w += (size_t)BATCH * HID * 2;
  hlo[1] = (unsigned short*)w;  w += (size_t)BATCH * HID * 2;
  float* cT = (float*)w;        w += (size_t)HID * BATCH * 4;
  size_t used = (size_t)(w - (char*)d_ws);

  // chunk size over timesteps, sized to fit ws (deterministic: ws_size const)
  size_t per_ct = ((size_t)INP * BATCH + (size_t)G4 * BATCH) * 4;  // Xt + XP per step
  int CT = 1;
  if (ws_size > used) {
    size_t avail = (ws_size - used) / per_ct;
    for (int c = SEQ; c >= 1; c >>= 1)
      if ((size_t)c <= avail) { CT = c; break; }
  }
  float* Xt = (float*)w;  w += (size_t)INP * BATCH * CT * 4;
  float* XP = (float*)w;
  int N = CT * BATCH;

  prepack_w<<<(256 * 32 * 64) / 256, 256, 0, stream>>>(W_hh, Whi, Wlo);
  init_state<<<BATCH * HID / 256, 256, 0, stream>>>(h0, c0, hhi[0], hlo[0], cT);

  for (int t0 = 0; t0 < SEQ; t0 += CT) {
    transpose_in<<<dim3(N / 32, INP / 32), 256, 0, stream>>>(
        inputs + (size_t)t0 * BATCH * INP, Xt, N);
    gemm_xproj<<<dim3(G4 / 128, N / 128), 256, 0, stream>>>(
        W_ih, Xt, b_ih, b_hh, XP, N);

    int Nv = N, CTv = CT, step0 = t0;
    void* kargs[] = {
        (void*)&Whi, (void*)&Wlo, (void*)&XP, (void*)&Nv, (void*)&CTv,
        (void*)&step0, (void*)&hhi[0], (void*)&hlo[0], (void*)&hhi[1],
        (void*)&hlo[1], (void*)&cT};
    hipLaunchCooperativeKernel((const void*)lstm_seq, dim3(256), dim3(256),
                               kargs, 0, stream);
  }

  // SEQ even -> final h in buffer 0
  decode_softmax<<<1, 512, 0, stream>>>(hhi[0], hlo[0], W_dec, b_dec, out);
}

// Round 3
// 17134.346 us; speedup vs baseline: 2.7366x; 2.7366x over previous
//
#include <hip/hip_runtime.h>
#include <math.h>

#define SEQ   512
#define BATCH 128
#define INP   512
#define HID   1024
#define G4    4096   // 4*HID
#define NOUT  4

typedef short bf16x8 __attribute__((ext_vector_type(8)));
typedef float f32x4  __attribute__((ext_vector_type(4)));

__device__ __forceinline__ unsigned short f2bf(float x) {  // RNE fp32->bf16
  unsigned int u = __float_as_uint(x);
  unsigned int r = (u + 0x7FFFu + ((u >> 16) & 1u)) >> 16;
  return (unsigned short)r;
}
__device__ __forceinline__ float bf2f(unsigned short h) {
  return __uint_as_float(((unsigned int)h) << 16);
}

// ---------------------------------------------------------------------------
// prepack W_hh [4096][1024] fp32 into fragment-linear bf16 hi/lo:
// out index ((bk4*32 + kstep)*64 + L)*8 + i  holds W[row][k] with
//   m = L&15, q = L>>4, g = m&3, jj = m>>2, row = g*HID + bk4*4 + jj,
//   k = kstep*32 + q*8 + i.
// Slab bk4 (4 j's) is contiguous (16384 shorts = 32 KB per buffer).
// ---------------------------------------------------------------------------
__global__ void prepack_w(const float* __restrict__ W,
                          unsigned short* __restrict__ Whi,
                          unsigned short* __restrict__ Wlo) {
  int T = blockIdx.x * blockDim.x + threadIdx.x;   // < 256*32*64
  int L = T & 63;
  int kstep = (T >> 6) & 31;
  int bk = T >> 11;
  int m = L & 15, q = L >> 4;
  int row = (m & 3) * HID + bk * 4 + (m >> 2);
  int k = kstep * 32 + q * 8;
  const float* src = W + (size_t)row * HID + k;
  unsigned short hi[8], lo[8];
#pragma unroll
  for (int i = 0; i < 8; i++) {
    float x = src[i];
    unsigned short h = f2bf(x);
    hi[i] = h;
    lo[i] = f2bf(x - bf2f(h));
  }
  size_t o = (size_t)T * 8;
#pragma unroll
  for (int i = 0; i < 8; i++) { Whi[o + i] = hi[i]; Wlo[o + i] = lo[i]; }
}

// ---------------------------------------------------------------------------
// init: h0 [B][H] fp32 -> h_hi/h_lo [B][H] bf16 (same layout);
//       c0 [B][H] -> cT [H][B] fp32 (transposed). Thread 0 zeroes both
//       barrier counters (monotonic across the whole sequence).
// ---------------------------------------------------------------------------
__global__ void init_state(const float* __restrict__ h0, const float* __restrict__ c0,
                           unsigned short* __restrict__ hhi, unsigned short* __restrict__ hlo,
                           float* __restrict__ cT, unsigned int* __restrict__ barcnt) {
  int idx = blockIdx.x * blockDim.x + threadIdx.x;  // < BATCH*HID
  if (idx == 0) { barcnt[0] = 0u; barcnt[32] = 0u; }
  int b = idx >> 10;          // h layout [b][j]
  int j = idx & (HID - 1);
  float x = h0[idx];
  unsigned short h = f2bf(x);
  hhi[idx] = h;
  hlo[idx] = f2bf(x - bf2f(h));
  cT[j * BATCH + b] = c0[idx];
}

// ---------------------------------------------------------------------------
// transpose a chunk of inputs: in [nrows][INP] -> xt [INP][nrows]
// ---------------------------------------------------------------------------
__global__ void transpose_in(const float* __restrict__ in, float* __restrict__ xt,
                             int nrows) {
  __shared__ float s[32][33];
  int tx = threadIdx.x & 31, ty = threadIdx.x >> 5;  // ty < 8
  int n0 = blockIdx.x * 32, i0 = blockIdx.y * 32;
#pragma unroll
  for (int r = 0; r < 4; r++) {
    int n = n0 + ty + 8 * r;
    s[ty + 8 * r][tx] = in[(size_t)n * INP + i0 + tx];
  }
  __syncthreads();
#pragma unroll
  for (int r = 0; r < 4; r++) {
    int i = i0 + ty + 8 * r;
    xt[(size_t)i * nrows + n0 + tx] = s[tx][ty + 8 * r];
  }
}

// ---------------------------------------------------------------------------
// gemm_xproj: C[4096][N] = W_ih[4096][512] @ Xt[512][N] + (b_ih + b_hh)
// (proven kernel, unchanged; MFMA conversion is the NEXT lever once the
// recurrent phase is fixed)
// ---------------------------------------------------------------------------
__global__ __launch_bounds__(256, 3)
void gemm_xproj(const float* __restrict__ A, const float* __restrict__ Bm,
                const float* __restrict__ b_ih, const float* __restrict__ b_hh,
                float* __restrict__ C, int N) {
  __shared__ float As[32][128];
  __shared__ float Bs[32][128];
  int t = threadIdx.x;
  int g0 = blockIdx.x * 128;
  int n0 = blockIdx.y * 128;
  int mg = (t >> 4) * 8, nn = (t & 15) * 8;
  float acc[8][8] = {};
  for (int k0 = 0; k0 < INP; k0 += 32) {
#pragma unroll
    for (int r = 0; r < 4; r++) {
      int idx = t + 256 * r;
      int g = idx >> 3, i4 = idx & 7;
      float4 v = *(const float4*)&A[(size_t)(g0 + g) * INP + k0 + 4 * i4];
      As[4 * i4 + 0][g] = v.x; As[4 * i4 + 1][g] = v.y;
      As[4 * i4 + 2][g] = v.z; As[4 * i4 + 3][g] = v.w;
    }
#pragma unroll
    for (int r = 0; r < 4; r++) {
      int idx = t + 256 * r;
      int kk = idx >> 5, n4 = idx & 31;
      *(float4*)&Bs[kk][4 * n4] = *(const float4*)&Bm[(size_t)(k0 + kk) * N + n0 + 4 * n4];
    }
    __syncthreads();
#pragma unroll 4
    for (int kk = 0; kk < 32; kk++) {
      float4 a0 = *(const float4*)&As[kk][mg];
      float4 a1 = *(const float4*)&As[kk][mg + 4];
      float4 bb0 = *(const float4*)&Bs[kk][nn];
      float4 bb1 = *(const float4*)&Bs[kk][nn + 4];
      float av[8] = {a0.x, a0.y, a0.z, a0.w, a1.x, a1.y, a1.z, a1.w};
      float bv[8] = {bb0.x, bb0.y, bb0.z, bb0.w, bb1.x, bb1.y, bb1.z, bb1.w};
#pragma unroll
      for (int i2 = 0; i2 < 8; i2++)
#pragma unroll
        for (int j2 = 0; j2 < 8; j2++)
          acc[i2][j2] = fmaf(av[i2], bv[j2], acc[i2][j2]);
    }
    __syncthreads();
  }
#pragma unroll
  for (int i2 = 0; i2 < 8; i2++) {
    int g = g0 + mg + i2;
    float bias = b_ih[g] + b_hh[g];
#pragma unroll
    for (int j2 = 0; j2 < 8; j2++) {
      C[(size_t)g * N + n0 + nn + j2] = acc[i2][j2] + bias;
    }
  }
}

// ---------------------------------------------------------------------------
// lstm_seq (R10): persistent kernel, HARDENED hand-rolled device barrier.
//
// R9 (hung, suspected): atomicAdd/AGENT-load may not carry the L2-bypass
// cache policy -> each XCD polls its own stale L2 copy -> deadlock.
// R10 barrier, per batch-half group (the two halves share NO data; 128
// blocks each, counters 128 B apart):
//   stores -> __syncthreads()            (vmcnt(0) for ALL waves)
//   lane 0: __threadfence_system()       (release: full WB past L2)
//           SYSTEM-scope fetch_add       (RMW at globally-coherent point)
//           poll SYSTEM-scope load       (bypasses L1+L2, sees all XCDs)
//             ... bounded: ~56 ms guard -> fast wrong-answer, never a hang
//           __threadfence_system()       (acquire: INV L1+L2)
//   __syncthreads()                      (hold readers until INV done)
// Monotonic counters (target = 128*(global_step+1)); no reset races.
// Skew is bounded to 1 step by the barrier; 2-buffer h ping-pong is safe
// under skew 1 (step k+1 writes the buffer whose step-k reads all
// completed before any block could pass barrier k).
//
// Tiling (R8, correctness-proven): 256 blocks x 256 thr (4 waves).
// Block bk: jblk=bk>>1 owns j=8*jblk..+7 (2 slabs, 128 KB LDS staged once
// per chunk); bk&1 owns batch half. W never leaves LDS; c in regs.
// ---------------------------------------------------------------------------
__global__ __launch_bounds__(256)
void lstm_seq(const unsigned short* __restrict__ Whi,
              const unsigned short* __restrict__ Wlo,
              const float* __restrict__ XP, int N, int CT, int step0,
              unsigned short* __restrict__ h0hi, unsigned short* __restrict__ h0lo,
              unsigned short* __restrict__ h1hi, unsigned short* __restrict__ h1lo,
              float* __restrict__ cT, unsigned int* barcnt) {
  __shared__ bf16x8 Wlds[8192];   // 128 KB: [0..4095]=hi (2 slabs), [4096..8191]=lo

  int bk = blockIdx.x;            // 0..255
  int jblk = bk >> 1;             // 0..127 -> j0 = 8*jblk
  int bh2 = bk & 1;               // batch half
  int t = threadIdx.x;            // 0..255
  int w = t >> 6;                 // wave 0..3
  int L = t & 63;
  int n = L & 15, q = L >> 4;
  int b = bh2 * 64 + w * 16 + n;
  int j0 = jblk * 8 + q;          // mt=0 row; mt=1 is j0+4

  unsigned int* mycnt = barcnt + bh2 * 32;   // per-half counter, 128 B apart

  // ---- stage BOTH W slabs (bk4 = 2*jblk, 2*jblk+1) into LDS once ----
  {
    float4* ldsf = (float4*)Wlds;
    const float4* s1 = (const float4*)(Whi + (size_t)jblk * 32768);
    const float4* s2 = (const float4*)(Wlo + (size_t)jblk * 32768);
#pragma unroll
    for (int i = 0; i < 16; i++) ldsf[t + 256 * i] = s1[t + 256 * i];
#pragma unroll
    for (int i = 0; i < 16; i++) ldsf[4096 + t + 256 * i] = s2[t + 256 * i];
  }

  int ci0 = j0 * BATCH + b;
  int ci1 = (j0 + 4) * BATCH + b;
  float cc0 = cT[ci0];            // c stays in registers for the whole chunk
  float cc1 = cT[ci1];

  size_t hoff = (size_t)b * HID + q * 8;
  size_t o0 = (size_t)b * HID + j0;

  __syncthreads();

  for (int tt = 0; tt < CT; tt++) {
    int gs = step0 + tt;
    int odd = gs & 1;
    const unsigned short* Bh = (odd ? h1hi : h0hi) + hoff;
    const unsigned short* Bl = (odd ? h1lo : h0lo) + hoff;
    unsigned short* dhi = odd ? h0hi : h1hi;
    unsigned short* dlo = odd ? h0lo : h1lo;
    const float* xpc = XP + (size_t)tt * BATCH;

    // xp prefetch (independent of h) — overlaps the MFMA loop
    float xpv0[4], xpv1[4];
#pragma unroll
    for (int g = 0; g < 4; g++) {
      xpv0[g] = xpc[(size_t)(g * HID + j0) * N + b];
      xpv1[g] = xpc[(size_t)(g * HID + j0 + 4) * N + b];
    }

    f32x4 acc0 = {0.f, 0.f, 0.f, 0.f};
    f32x4 acc1 = {0.f, 0.f, 0.f, 0.f};
#pragma unroll 4
    for (int ks = 0; ks < 32; ks++) {
      bf16x8 bhv = *(const bf16x8*)(Bh + ks * 32);
      bf16x8 blv = *(const bf16x8*)(Bl + ks * 32);
      bf16x8 ah0 = Wlds[ks * 64 + L];
      bf16x8 ah1 = Wlds[2048 + ks * 64 + L];
      bf16x8 al0 = Wlds[4096 + ks * 64 + L];
      bf16x8 al1 = Wlds[6144 + ks * 64 + L];
      acc0 = __builtin_amdgcn_mfma_f32_16x16x32_bf16(ah0, bhv, acc0, 0, 0, 0);
      acc1 = __builtin_amdgcn_mfma_f32_16x16x32_bf16(ah1, bhv, acc1, 0, 0, 0);
      acc0 = __builtin_amdgcn_mfma_f32_16x16x32_bf16(ah0, blv, acc0, 0, 0, 0);
      acc1 = __builtin_amdgcn_mfma_f32_16x16x32_bf16(ah1, blv, acc1, 0, 0, 0);
      acc0 = __builtin_amdgcn_mfma_f32_16x16x32_bf16(al0, bhv, acc0, 0, 0, 0);
      acc1 = __builtin_amdgcn_mfma_f32_16x16x32_bf16(al1, bhv, acc1, 0, 0, 0);
    }

    {   // cell update, M-tile 0 (j = j0)
      float i_ = 1.f / (1.f + expf(-(acc0[0] + xpv0[0])));
      float f_ = 1.f / (1.f + expf(-(acc0[1] + xpv0[1])));
      float g_ = tanhf(acc0[2] + xpv0[2]);
      float o_ = 1.f / (1.f + expf(-(acc0[3] + xpv0[3])));
      cc0 = f_ * cc0 + i_ * g_;
      float hn = o_ * tanhf(cc0);
      unsigned short hh = f2bf(hn);
      dhi[o0] = hh;
      dlo[o0] = f2bf(hn - bf2f(hh));
    }
    {   // cell update, M-tile 1 (j = j0+4)
      float i_ = 1.f / (1.f + expf(-(acc1[0] + xpv1[0])));
      float f_ = 1.f / (1.f + expf(-(acc1[1] + xpv1[1])));
      float g_ = tanhf(acc1[2] + xpv1[2]);
      float o_ = 1.f / (1.f + expf(-(acc1[3] + xpv1[3])));
      cc1 = f_ * cc1 + i_ * g_;
      float hn = o_ * tanhf(cc1);
      unsigned short hh = f2bf(hn);
      dhi[o0 + 4] = hh;
      dlo[o0 + 4] = f2bf(hn - bf2f(hh));
    }

    // ---- hardened device barrier (per batch-half; 128 participants) ----
    __syncthreads();   // all waves' h stores drained (vmcnt(0) at barrier)
    if (t == 0) {
      __threadfence_system();                  // release: WB past L2 (all dirty)
      __hip_atomic_fetch_add(mycnt, 1u, __ATOMIC_RELAXED,
                             __HIP_MEMORY_SCOPE_SYSTEM);
      unsigned tgt = 128u * (unsigned)(gs + 1);
      int guard = 0;
      while (__hip_atomic_load(mycnt, __ATOMIC_RELAXED,
                               __HIP_MEMORY_SCOPE_SYSTEM) < tgt &&
             guard < (1 << 18)) {              // ~56 ms max: hang -> wrong ans
        __builtin_amdgcn_s_sleep(8);
        ++guard;
      }
      __threadfence_system();                  // acquire: INV L1 + L2
    }
    __syncthreads();   // hold all waves until invalidate is done
  }

  cT[ci0] = cc0;
  cT[ci1] = cc1;
}

// ---------------------------------------------------------------------------
// decode + softmax over batch dim (axis 0); h from hi+lo bf16 [B][H]
// ---------------------------------------------------------------------------
__global__ void decode_softmax(const unsigned short* __restrict__ hhi,
                               const unsigned short* __restrict__ hlo,
                               const float* __restrict__ Wd,
                               const float* __restrict__ bd, float* __restrict__ out) {
  __shared__ float lg[NOUT][BATCH];
  __shared__ float mx[NOUT], sm[NOUT];
  int t = threadIdx.x;  // 512 threads
  int b = t >> 2, o = t & 3;
  float s = bd[o];
  for (int j = 0; j < HID; j++) {
    float hv = bf2f(hhi[(size_t)b * HID + j]) + bf2f(hlo[(size_t)b * HID + j]);
    s += hv * Wd[o * HID + j];
  }
  lg[o][b] = s;
  __syncthreads();
  if (t < NOUT) {
    float m = -1e30f;
    for (int b2 = 0; b2 < BATCH; b2++) m = fmaxf(m, lg[t][b2]);
    float ss = 0.f;
    for (int b2 = 0; b2 < BATCH; b2++) ss += expf(lg[t][b2] - m);
    mx[t] = m; sm[t] = ss;
  }
  __syncthreads();
  out[b * NOUT + o] = expf(lg[o][b] - mx[o]) / sm[o];
}

// ---------------------------------------------------------------------------
extern "C" void kernel_launch(void* const* d_in, const int* in_sizes, int n_in,
                              void* d_out, int out_size, void* d_ws, size_t ws_size,
                              hipStream_t stream) {
  const float* inputs = (const float*)d_in[0];
  const float* h0     = (const float*)d_in[1];
  const float* c0     = (const float*)d_in[2];
  const float* W_ih   = (const float*)d_in[3];
  const float* W_hh   = (const float*)d_in[4];
  const float* b_ih   = (const float*)d_in[5];
  const float* b_hh   = (const float*)d_in[6];
  const float* W_dec  = (const float*)d_in[7];
  const float* b_dec  = (const float*)d_in[8];
  float* out = (float*)d_out;

  char* w = (char*)d_ws;
  unsigned short* Whi = (unsigned short*)w;  w += (size_t)G4 * HID * 2;
  unsigned short* Wlo = (unsigned short*)w;  w += (size_t)G4 * HID * 2;
  unsigned short* hhi[2], *hlo[2];
  hhi[0] = (unsigned short*)w;  w += (size_t)BATCH * HID * 2;
  hhi[1] = (unsigned short*)w;  w += (size_t)BATCH * HID * 2;
  hlo[0] = (unsigned short*)w;  w += (size_t)BATCH * HID * 2;
  hlo[1] = (unsigned short*)w;  w += (size_t)BATCH * HID * 2;
  float* cT = (float*)w;        w += (size_t)HID * BATCH * 4;
  unsigned int* barcnt = (unsigned int*)w;  w += 256;   // 2 counters, 128 B apart
  size_t used = (size_t)(w - (char*)d_ws);

  // chunk size over timesteps, sized to fit ws (deterministic: ws_size const)
  size_t per_ct = ((size_t)INP * BATCH + (size_t)G4 * BATCH) * 4;  // Xt + XP per step
  int CT = 1;
  if (ws_size > used) {
    size_t avail = (ws_size - used) / per_ct;
    for (int c = SEQ; c >= 1; c >>= 1)
      if ((size_t)c <= avail) { CT = c; break; }
  }
  float* Xt = (float*)w;  w += (size_t)INP * BATCH * CT * 4;
  float* XP = (float*)w;
  int N = CT * BATCH;

  prepack_w<<<(256 * 32 * 64) / 256, 256, 0, stream>>>(W_hh, Whi, Wlo);
  init_state<<<BATCH * HID / 256, 256, 0, stream>>>(h0, c0, hhi[0], hlo[0], cT, barcnt);

  for (int t0 = 0; t0 < SEQ; t0 += CT) {
    transpose_in<<<dim3(N / 32, INP / 32), 256, 0, stream>>>(
        inputs + (size_t)t0 * BATCH * INP, Xt, N);
    gemm_xproj<<<dim3(G4 / 128, N / 128), 256, 0, stream>>>(
        W_ih, Xt, b_ih, b_hh, XP, N);

    int Nv = N, CTv = CT, step0 = t0;
    void* kargs[] = {
        (void*)&Whi, (void*)&Wlo, (void*)&XP, (void*)&Nv, (void*)&CTv,
        (void*)&step0, (void*)&hhi[0], (void*)&hlo[0], (void*)&hhi[1],
        (void*)&hlo[1], (void*)&cT, (void*)&barcnt};
    hipLaunchCooperativeKernel((const void*)lstm_seq, dim3(256), dim3(256),
                               kargs, 0, stream);
  }

  // SEQ even -> final h in buffer 0
  decode_softmax<<<1, 512, 0, stream>>>(hhi[0], hlo[0], W_dec, b_dec, out);
}

// Round 4
// 16742.116 us; speedup vs baseline: 2.8007x; 1.0234x over previous
//
#include <hip/hip_runtime.h>
#include <math.h>

#define SEQ   512
#define BATCH 128
#define INP   512
#define HID   1024
#define G4    4096   // 4*HID
#define NOUT  4

typedef short bf16x8 __attribute__((ext_vector_type(8)));
typedef float f32x4  __attribute__((ext_vector_type(4)));

__device__ __forceinline__ unsigned short f2bf(float x) {  // RNE fp32->bf16
  unsigned int u = __float_as_uint(x);
  unsigned int r = (u + 0x7FFFu + ((u >> 16) & 1u)) >> 16;
  return (unsigned short)r;
}
__device__ __forceinline__ float bf2f(unsigned short h) {
  return __uint_as_float(((unsigned int)h) << 16);
}

// ---------------------------------------------------------------------------
// prepack W_hh [4096][1024] fp32 into fragment-linear bf16 hi/lo:
// out index ((bk4*32 + kstep)*64 + L)*8 + i  holds W[row][k] with
//   m = L&15, q = L>>4, g = m&3, jj = m>>2, row = g*HID + bk4*4 + jj,
//   k = kstep*32 + q*8 + i.
// Slab bk4 (4 j's) is contiguous (16384 shorts = 32 KB per buffer).
// ---------------------------------------------------------------------------
__global__ void prepack_w(const float* __restrict__ W,
                          unsigned short* __restrict__ Whi,
                          unsigned short* __restrict__ Wlo) {
  int T = blockIdx.x * blockDim.x + threadIdx.x;   // < 256*32*64
  int L = T & 63;
  int kstep = (T >> 6) & 31;
  int bk = T >> 11;
  int m = L & 15, q = L >> 4;
  int row = (m & 3) * HID + bk * 4 + (m >> 2);
  int k = kstep * 32 + q * 8;
  const float* src = W + (size_t)row * HID + k;
  unsigned short hi[8], lo[8];
#pragma unroll
  for (int i = 0; i < 8; i++) {
    float x = src[i];
    unsigned short h = f2bf(x);
    hi[i] = h;
    lo[i] = f2bf(x - bf2f(h));
  }
  size_t o = (size_t)T * 8;
#pragma unroll
  for (int i = 0; i < 8; i++) { Whi[o + i] = hi[i]; Wlo[o + i] = lo[i]; }
}

// ---------------------------------------------------------------------------
// init: h0 [B][H] fp32 -> h_hi/h_lo [B][H] bf16 (same layout);
//       c0 [B][H] -> cT [H][B] fp32 (transposed). Threads 0..255 zero the
//       barrier flag array (monotonic across the whole sequence).
// ---------------------------------------------------------------------------
__global__ void init_state(const float* __restrict__ h0, const float* __restrict__ c0,
                           unsigned short* __restrict__ hhi, unsigned short* __restrict__ hlo,
                           float* __restrict__ cT, unsigned int* __restrict__ flags) {
  int idx = blockIdx.x * blockDim.x + threadIdx.x;  // < BATCH*HID
  if (idx < 256) flags[idx] = 0u;
  int b = idx >> 10;          // h layout [b][j]
  int j = idx & (HID - 1);
  float x = h0[idx];
  unsigned short h = f2bf(x);
  hhi[idx] = h;
  hlo[idx] = f2bf(x - bf2f(h));
  cT[j * BATCH + b] = c0[idx];
}

// ---------------------------------------------------------------------------
// transpose a chunk of inputs: in [nrows][INP] -> xt [INP][nrows]
// ---------------------------------------------------------------------------
__global__ void transpose_in(const float* __restrict__ in, float* __restrict__ xt,
                             int nrows) {
  __shared__ float s[32][33];
  int tx = threadIdx.x & 31, ty = threadIdx.x >> 5;  // ty < 8
  int n0 = blockIdx.x * 32, i0 = blockIdx.y * 32;
#pragma unroll
  for (int r = 0; r < 4; r++) {
    int n = n0 + ty + 8 * r;
    s[ty + 8 * r][tx] = in[(size_t)n * INP + i0 + tx];
  }
  __syncthreads();
#pragma unroll
  for (int r = 0; r < 4; r++) {
    int i = i0 + ty + 8 * r;
    xt[(size_t)i * nrows + n0 + tx] = s[tx][ty + 8 * r];
  }
}

// ---------------------------------------------------------------------------
// gemm_xproj: C[4096][N] = W_ih[4096][512] @ Xt[512][N] + (b_ih + b_hh)
// (proven kernel, unchanged; ~73% of fp32 vector peak. hi/lo-bf16 MFMA
// conversion is the NEXT lever once the recurrent phase is fixed)
// ---------------------------------------------------------------------------
__global__ __launch_bounds__(256, 3)
void gemm_xproj(const float* __restrict__ A, const float* __restrict__ Bm,
                const float* __restrict__ b_ih, const float* __restrict__ b_hh,
                float* __restrict__ C, int N) {
  __shared__ float As[32][128];
  __shared__ float Bs[32][128];
  int t = threadIdx.x;
  int g0 = blockIdx.x * 128;
  int n0 = blockIdx.y * 128;
  int mg = (t >> 4) * 8, nn = (t & 15) * 8;
  float acc[8][8] = {};
  for (int k0 = 0; k0 < INP; k0 += 32) {
#pragma unroll
    for (int r = 0; r < 4; r++) {
      int idx = t + 256 * r;
      int g = idx >> 3, i4 = idx & 7;
      float4 v = *(const float4*)&A[(size_t)(g0 + g) * INP + k0 + 4 * i4];
      As[4 * i4 + 0][g] = v.x; As[4 * i4 + 1][g] = v.y;
      As[4 * i4 + 2][g] = v.z; As[4 * i4 + 3][g] = v.w;
    }
#pragma unroll
    for (int r = 0; r < 4; r++) {
      int idx = t + 256 * r;
      int kk = idx >> 5, n4 = idx & 31;
      *(float4*)&Bs[kk][4 * n4] = *(const float4*)&Bm[(size_t)(k0 + kk) * N + n0 + 4 * n4];
    }
    __syncthreads();
#pragma unroll 4
    for (int kk = 0; kk < 32; kk++) {
      float4 a0 = *(const float4*)&As[kk][mg];
      float4 a1 = *(const float4*)&As[kk][mg + 4];
      float4 bb0 = *(const float4*)&Bs[kk][nn];
      float4 bb1 = *(const float4*)&Bs[kk][nn + 4];
      float av[8] = {a0.x, a0.y, a0.z, a0.w, a1.x, a1.y, a1.z, a1.w};
      float bv[8] = {bb0.x, bb0.y, bb0.z, bb0.w, bb1.x, bb1.y, bb1.z, bb1.w};
#pragma unroll
      for (int i2 = 0; i2 < 8; i2++)
#pragma unroll
        for (int j2 = 0; j2 < 8; j2++)
          acc[i2][j2] = fmaf(av[i2], bv[j2], acc[i2][j2]);
    }
    __syncthreads();
  }
#pragma unroll
  for (int i2 = 0; i2 < 8; i2++) {
    int g = g0 + mg + i2;
    float bias = b_ih[g] + b_hh[g];
#pragma unroll
    for (int j2 = 0; j2 < 8; j2++) {
      C[(size_t)g * N + n0 + nn + j2] = acc[i2][j2] + bias;
    }
  }
}

// ---------------------------------------------------------------------------
// lstm_seq (R11): persistent kernel; FLAG-ARRAY barrier (no RMW hot-spot).
//
// R10 post-mortem: 27.7 us/step with MfmaUtil 4.8% -> ~23 us is barrier;
// scaling vs R8 (256-way counter, 87 us) fingerprints the serialized
// system-scope fetch_add chain (128 RMWs x ~0.18 us on one line). R11
// keeps R10's proven fence structure but makes arrival RMW-free:
//   stores -> __syncthreads()          (vmcnt(0) for ALL waves)
//   t==0:  __threadfence_system()      (release: WB L2 past coherence pt)
//          system-scope STORE flags[slot]=gs+1   (posted, no round-trip)
//   all threads: sweep my half's 128 flags (1 coalesced system load/thread,
//          lanes 128..255 auto-pass), __syncthreads_and, repeat (bounded)
//   t==0:  __threadfence_system()      (acquire: INV L1+L2)
//   __syncthreads()
// Halves are data-independent (disjoint h rows, disjoint flag lines).
// Monotonic flags -> no reset races. Bounded sweep -> no hang, worst case
// fast-wrong-answer.
//
// Tiling (R8/R10, correctness-proven): 256 blocks x 256 thr (4 waves).
// Block bk: jblk=bk>>1 owns j=8*jblk..+7 (2 slabs, 128 KB LDS staged once
// per chunk); bk&1 owns batch half. W never leaves LDS; c in regs.
// ---------------------------------------------------------------------------
__global__ __launch_bounds__(256)
void lstm_seq(const unsigned short* __restrict__ Whi,
              const unsigned short* __restrict__ Wlo,
              const float* __restrict__ XP, int N, int CT, int step0,
              unsigned short* __restrict__ h0hi, unsigned short* __restrict__ h0lo,
              unsigned short* __restrict__ h1hi, unsigned short* __restrict__ h1lo,
              float* __restrict__ cT, unsigned int* flags) {
  __shared__ bf16x8 Wlds[8192];   // 128 KB: [0..4095]=hi (2 slabs), [4096..8191]=lo

  int bk = blockIdx.x;            // 0..255
  int jblk = bk >> 1;             // 0..127 -> j0 = 8*jblk
  int bh2 = bk & 1;               // batch half
  int t = threadIdx.x;            // 0..255
  int w = t >> 6;                 // wave 0..3
  int L = t & 63;
  int n = L & 15, q = L >> 4;
  int b = bh2 * 64 + w * 16 + n;
  int j0 = jblk * 8 + q;          // mt=0 row; mt=1 is j0+4

  unsigned int* myflags = flags + bh2 * 128;   // my half's flag group (512 B)

  // ---- stage BOTH W slabs (bk4 = 2*jblk, 2*jblk+1) into LDS once ----
  {
    float4* ldsf = (float4*)Wlds;
    const float4* s1 = (const float4*)(Whi + (size_t)jblk * 32768);
    const float4* s2 = (const float4*)(Wlo + (size_t)jblk * 32768);
#pragma unroll
    for (int i = 0; i < 16; i++) ldsf[t + 256 * i] = s1[t + 256 * i];
#pragma unroll
    for (int i = 0; i < 16; i++) ldsf[4096 + t + 256 * i] = s2[t + 256 * i];
  }

  int ci0 = j0 * BATCH + b;
  int ci1 = (j0 + 4) * BATCH + b;
  float cc0 = cT[ci0];            // c stays in registers for the whole chunk
  float cc1 = cT[ci1];

  size_t hoff = (size_t)b * HID + q * 8;
  size_t o0 = (size_t)b * HID + j0;

  __syncthreads();

  for (int tt = 0; tt < CT; tt++) {
    int gs = step0 + tt;
    int odd = gs & 1;
    const unsigned short* Bh = (odd ? h1hi : h0hi) + hoff;
    const unsigned short* Bl = (odd ? h1lo : h0lo) + hoff;
    unsigned short* dhi = odd ? h0hi : h1hi;
    unsigned short* dlo = odd ? h0lo : h1lo;
    const float* xpc = XP + (size_t)tt * BATCH;

    // xp prefetch (independent of h) — overlaps the MFMA loop
    float xpv0[4], xpv1[4];
#pragma unroll
    for (int g = 0; g < 4; g++) {
      xpv0[g] = xpc[(size_t)(g * HID + j0) * N + b];
      xpv1[g] = xpc[(size_t)(g * HID + j0 + 4) * N + b];
    }

    f32x4 acc0 = {0.f, 0.f, 0.f, 0.f};
    f32x4 acc1 = {0.f, 0.f, 0.f, 0.f};
#pragma unroll 4
    for (int ks = 0; ks < 32; ks++) {
      bf16x8 bhv = *(const bf16x8*)(Bh + ks * 32);
      bf16x8 blv = *(const bf16x8*)(Bl + ks * 32);
      bf16x8 ah0 = Wlds[ks * 64 + L];
      bf16x8 ah1 = Wlds[2048 + ks * 64 + L];
      bf16x8 al0 = Wlds[4096 + ks * 64 + L];
      bf16x8 al1 = Wlds[6144 + ks * 64 + L];
      acc0 = __builtin_amdgcn_mfma_f32_16x16x32_bf16(ah0, bhv, acc0, 0, 0, 0);
      acc1 = __builtin_amdgcn_mfma_f32_16x16x32_bf16(ah1, bhv, acc1, 0, 0, 0);
      acc0 = __builtin_amdgcn_mfma_f32_16x16x32_bf16(ah0, blv, acc0, 0, 0, 0);
      acc1 = __builtin_amdgcn_mfma_f32_16x16x32_bf16(ah1, blv, acc1, 0, 0, 0);
      acc0 = __builtin_amdgcn_mfma_f32_16x16x32_bf16(al0, bhv, acc0, 0, 0, 0);
      acc1 = __builtin_amdgcn_mfma_f32_16x16x32_bf16(al1, bhv, acc1, 0, 0, 0);
    }

    {   // cell update, M-tile 0 (j = j0)
      float i_ = 1.f / (1.f + expf(-(acc0[0] + xpv0[0])));
      float f_ = 1.f / (1.f + expf(-(acc0[1] + xpv0[1])));
      float g_ = tanhf(acc0[2] + xpv0[2]);
      float o_ = 1.f / (1.f + expf(-(acc0[3] + xpv0[3])));
      cc0 = f_ * cc0 + i_ * g_;
      float hn = o_ * tanhf(cc0);
      unsigned short hh = f2bf(hn);
      dhi[o0] = hh;
      dlo[o0] = f2bf(hn - bf2f(hh));
    }
    {   // cell update, M-tile 1 (j = j0+4)
      float i_ = 1.f / (1.f + expf(-(acc1[0] + xpv1[0])));
      float f_ = 1.f / (1.f + expf(-(acc1[1] + xpv1[1])));
      float g_ = tanhf(acc1[2] + xpv1[2]);
      float o_ = 1.f / (1.f + expf(-(acc1[3] + xpv1[3])));
      cc1 = f_ * cc1 + i_ * g_;
      float hn = o_ * tanhf(cc1);
      unsigned short hh = f2bf(hn);
      dhi[o0 + 4] = hh;
      dlo[o0 + 4] = f2bf(hn - bf2f(hh));
    }

    // ---- flag-array device barrier (per batch-half; RMW-free) ----
    unsigned tgt = (unsigned)(gs + 1);
    __syncthreads();   // all waves' h stores drained (vmcnt(0) at barrier)
    if (t == 0) {
      __threadfence_system();                  // release: WB past L2
      __hip_atomic_store(&myflags[jblk], tgt, __ATOMIC_RELAXED,
                         __HIP_MEMORY_SCOPE_SYSTEM);   // posted arrival
    }
    {
      int sweeps = 0;
      for (;;) {
        int ok = 1;
        if (t < 128)
          ok = (__hip_atomic_load(&myflags[t], __ATOMIC_RELAXED,
                                  __HIP_MEMORY_SCOPE_SYSTEM) >= tgt);
        if (__syncthreads_and(ok)) break;
        if (++sweeps > (1 << 16)) break;       // ~>50 ms: wrong ans, no hang
      }
    }
    if (t == 0) __threadfence_system();        // acquire: INV L1 + L2
    __syncthreads();   // hold all waves until invalidate is done
  }

  cT[ci0] = cc0;
  cT[ci1] = cc1;
}

// ---------------------------------------------------------------------------
// decode + softmax over batch dim (axis 0); h from hi+lo bf16 [B][H]
// ---------------------------------------------------------------------------
__global__ void decode_softmax(const unsigned short* __restrict__ hhi,
                               const unsigned short* __restrict__ hlo,
                               const float* __restrict__ Wd,
                               const float* __restrict__ bd, float* __restrict__ out) {
  __shared__ float lg[NOUT][BATCH];
  __shared__ float mx[NOUT], sm[NOUT];
  int t = threadIdx.x;  // 512 threads
  int b = t >> 2, o = t & 3;
  float s = bd[o];
  for (int j = 0; j < HID; j++) {
    float hv = bf2f(hhi[(size_t)b * HID + j]) + bf2f(hlo[(size_t)b * HID + j]);
    s += hv * Wd[o * HID + j];
  }
  lg[o][b] = s;
  __syncthreads();
  if (t < NOUT) {
    float m = -1e30f;
    for (int b2 = 0; b2 < BATCH; b2++) m = fmaxf(m, lg[t][b2]);
    float ss = 0.f;
    for (int b2 = 0; b2 < BATCH; b2++) ss += expf(lg[t][b2] - m);
    mx[t] = m; sm[t] = ss;
  }
  __syncthreads();
  out[b * NOUT + o] = expf(lg[o][b] - mx[o]) / sm[o];
}

// ---------------------------------------------------------------------------
extern "C" void kernel_launch(void* const* d_in, const int* in_sizes, int n_in,
                              void* d_out, int out_size, void* d_ws, size_t ws_size,
                              hipStream_t stream) {
  const float* inputs = (const float*)d_in[0];
  const float* h0     = (const float*)d_in[1];
  const float* c0     = (const float*)d_in[2];
  const float* W_ih   = (const float*)d_in[3];
  const float* W_hh   = (const float*)d_in[4];
  const float* b_ih   = (const float*)d_in[5];
  const float* b_hh   = (const float*)d_in[6];
  const float* W_dec  = (const float*)d_in[7];
  const float* b_dec  = (const float*)d_in[8];
  float* out = (float*)d_out;

  char* w = (char*)d_ws;
  unsigned short* Whi = (unsigned short*)w;  w += (size_t)G4 * HID * 2;
  unsigned short* Wlo = (unsigned short*)w;  w += (size_t)G4 * HID * 2;
  unsigned short* hhi[2], *hlo[2];
  hhi[0] = (unsigned short*)w;  w += (size_t)BATCH * HID * 2;
  hhi[1] = (unsigned short*)w;  w += (size_t)BATCH * HID * 2;
  hlo[0] = (unsigned short*)w;  w += (size_t)BATCH * HID * 2;
  hlo[1] = (unsigned short*)w;  w += (size_t)BATCH * HID * 2;
  float* cT = (float*)w;        w += (size_t)HID * BATCH * 4;
  unsigned int* flags = (unsigned int*)w;  w += 1024;   // 256 flags (2 halves)
  size_t used = (size_t)(w - (char*)d_ws);

  // chunk size over timesteps, sized to fit ws (deterministic: ws_size const)
  size_t per_ct = ((size_t)INP * BATCH + (size_t)G4 * BATCH) * 4;  // Xt + XP per step
  int CT = 1;
  if (ws_size > used) {
    size_t avail = (ws_size - used) / per_ct;
    for (int c = SEQ; c >= 1; c >>= 1)
      if ((size_t)c <= avail) { CT = c; break; }
  }
  float* Xt = (float*)w;  w += (size_t)INP * BATCH * CT * 4;
  float* XP = (float*)w;
  int N = CT * BATCH;

  prepack_w<<<(256 * 32 * 64) / 256, 256, 0, stream>>>(W_hh, Whi, Wlo);
  init_state<<<BATCH * HID / 256, 256, 0, stream>>>(h0, c0, hhi[0], hlo[0], cT, flags);

  for (int t0 = 0; t0 < SEQ; t0 += CT) {
    transpose_in<<<dim3(N / 32, INP / 32), 256, 0, stream>>>(
        inputs + (size_t)t0 * BATCH * INP, Xt, N);
    gemm_xproj<<<dim3(G4 / 128, N / 128), 256, 0, stream>>>(
        W_ih, Xt, b_ih, b_hh, XP, N);

    int Nv = N, CTv = CT, step0 = t0;
    void* kargs[] = {
        (void*)&Whi, (void*)&Wlo, (void*)&XP, (void*)&Nv, (void*)&CTv,
        (void*)&step0, (void*)&hhi[0], (void*)&hlo[0], (void*)&hhi[1],
        (void*)&hlo[1], (void*)&cT, (void*)&flags};
    hipLaunchCooperativeKernel((const void*)lstm_seq, dim3(256), dim3(256),
                               kargs, 0, stream);
  }

  // SEQ even -> final h in buffer 0
  decode_softmax<<<1, 512, 0, stream>>>(hhi[0], hlo[0], W_dec, b_dec, out);
}

// Round 5
// 12500.770 us; speedup vs baseline: 3.7510x; 1.3393x over previous
//
#include <hip/hip_runtime.h>
#include <math.h>

#define SEQ   512
#define BATCH 128
#define INP   512
#define HID   1024
#define G4    4096   // 4*HID
#define NOUT  4
#define GO_IDX 384   // go-word slot in flags[], separate 128B line from 0..255

typedef short bf16x8 __attribute__((ext_vector_type(8)));
typedef float f32x4  __attribute__((ext_vector_type(4)));

__device__ __forceinline__ unsigned short f2bf(float x) {  // RNE fp32->bf16
  unsigned int u = __float_as_uint(x);
  unsigned int r = (u + 0x7FFFu + ((u >> 16) & 1u)) >> 16;
  return (unsigned short)r;
}
__device__ __forceinline__ float bf2f(unsigned short h) {
  return __uint_as_float(((unsigned int)h) << 16);
}

// uncached (system-scope, sc0+sc1) 16B load as 2x u64: bypasses L1+L2 so
// remote-XCD h writes are visible WITHOUT any cache-maintenance fences.
__device__ __forceinline__ bf16x8 ld_h16_uc(const unsigned short* p) {
  union { unsigned long long q[2]; bf16x8 v; } u;
  unsigned long long* pp = (unsigned long long*)(void*)p;
  u.q[0] = __hip_atomic_load(pp,     __ATOMIC_RELAXED, __HIP_MEMORY_SCOPE_SYSTEM);
  u.q[1] = __hip_atomic_load(pp + 1, __ATOMIC_RELAXED, __HIP_MEMORY_SCOPE_SYSTEM);
  return u.v;
}

// ---------------------------------------------------------------------------
// prepack W_hh [4096][1024] fp32 into fragment-linear bf16 hi/lo:
// out index ((bk4*32 + kstep)*64 + L)*8 + i  holds W[row][k] with
//   m = L&15, q = L>>4, g = m&3, jj = m>>2, row = g*HID + bk4*4 + jj,
//   k = kstep*32 + q*8 + i.
// Slab bk4 (4 j's) is contiguous (16384 shorts = 32 KB per buffer).
// ---------------------------------------------------------------------------
__global__ void prepack_w(const float* __restrict__ W,
                          unsigned short* __restrict__ Whi,
                          unsigned short* __restrict__ Wlo) {
  int T = blockIdx.x * blockDim.x + threadIdx.x;   // < 256*32*64
  int L = T & 63;
  int kstep = (T >> 6) & 31;
  int bk = T >> 11;
  int m = L & 15, q = L >> 4;
  int row = (m & 3) * HID + bk * 4 + (m >> 2);
  int k = kstep * 32 + q * 8;
  const float* src = W + (size_t)row * HID + k;
  unsigned short hi[8], lo[8];
#pragma unroll
  for (int i = 0; i < 8; i++) {
    float x = src[i];
    unsigned short h = f2bf(x);
    hi[i] = h;
    lo[i] = f2bf(x - bf2f(h));
  }
  size_t o = (size_t)T * 8;
#pragma unroll
  for (int i = 0; i < 8; i++) { Whi[o + i] = hi[i]; Wlo[o + i] = lo[i]; }
}

// ---------------------------------------------------------------------------
// init: h0 [B][H] fp32 -> h_hi/h_lo [B][H] bf16 (same layout);
//       c0 [B][H] -> cT [H][B] fp32 (transposed). Threads 0..511 zero the
//       barrier flag array + go word (monotonic across the whole sequence).
// ---------------------------------------------------------------------------
__global__ void init_state(const float* __restrict__ h0, const float* __restrict__ c0,
                           unsigned short* __restrict__ hhi, unsigned short* __restrict__ hlo,
                           float* __restrict__ cT, unsigned int* __restrict__ flags) {
  int idx = blockIdx.x * blockDim.x + threadIdx.x;  // < BATCH*HID
  if (idx < 512) flags[idx] = 0u;
  int b = idx >> 10;          // h layout [b][j]
  int j = idx & (HID - 1);
  float x = h0[idx];
  unsigned short h = f2bf(x);
  hhi[idx] = h;
  hlo[idx] = f2bf(x - bf2f(h));
  cT[j * BATCH + b] = c0[idx];
}

// ---------------------------------------------------------------------------
// transpose a chunk of inputs: in [nrows][INP] -> xt [INP][nrows]
// ---------------------------------------------------------------------------
__global__ void transpose_in(const float* __restrict__ in, float* __restrict__ xt,
                             int nrows) {
  __shared__ float s[32][33];
  int tx = threadIdx.x & 31, ty = threadIdx.x >> 5;  // ty < 8
  int n0 = blockIdx.x * 32, i0 = blockIdx.y * 32;
#pragma unroll
  for (int r = 0; r < 4; r++) {
    int n = n0 + ty + 8 * r;
    s[ty + 8 * r][tx] = in[(size_t)n * INP + i0 + tx];
  }
  __syncthreads();
#pragma unroll
  for (int r = 0; r < 4; r++) {
    int i = i0 + ty + 8 * r;
    xt[(size_t)i * nrows + n0 + tx] = s[tx][ty + 8 * r];
  }
}

// ---------------------------------------------------------------------------
// gemm_xproj: C[4096][N] = W_ih[4096][512] @ Xt[512][N] + (b_ih + b_hh)
// (proven kernel, unchanged; ~73% of fp32 vector peak. hi/lo-bf16 MFMA
// conversion is the NEXT lever once the recurrent phase is fixed)
// ---------------------------------------------------------------------------
__global__ __launch_bounds__(256, 3)
void gemm_xproj(const float* __restrict__ A, const float* __restrict__ Bm,
                const float* __restrict__ b_ih, const float* __restrict__ b_hh,
                float* __restrict__ C, int N) {
  __shared__ float As[32][128];
  __shared__ float Bs[32][128];
  int t = threadIdx.x;
  int g0 = blockIdx.x * 128;
  int n0 = blockIdx.y * 128;
  int mg = (t >> 4) * 8, nn = (t & 15) * 8;
  float acc[8][8] = {};
  for (int k0 = 0; k0 < INP; k0 += 32) {
#pragma unroll
    for (int r = 0; r < 4; r++) {
      int idx = t + 256 * r;
      int g = idx >> 3, i4 = idx & 7;
      float4 v = *(const float4*)&A[(size_t)(g0 + g) * INP + k0 + 4 * i4];
      As[4 * i4 + 0][g] = v.x; As[4 * i4 + 1][g] = v.y;
      As[4 * i4 + 2][g] = v.z; As[4 * i4 + 3][g] = v.w;
    }
#pragma unroll
    for (int r = 0; r < 4; r++) {
      int idx = t + 256 * r;
      int kk = idx >> 5, n4 = idx & 31;
      *(float4*)&Bs[kk][4 * n4] = *(const float4*)&Bm[(size_t)(k0 + kk) * N + n0 + 4 * n4];
    }
    __syncthreads();
#pragma unroll 4
    for (int kk = 0; kk < 32; kk++) {
      float4 a0 = *(const float4*)&As[kk][mg];
      float4 a1 = *(const float4*)&As[kk][mg + 4];
      float4 bb0 = *(const float4*)&Bs[kk][nn];
      float4 bb1 = *(const float4*)&Bs[kk][nn + 4];
      float av[8] = {a0.x, a0.y, a0.z, a0.w, a1.x, a1.y, a1.z, a1.w};
      float bv[8] = {bb0.x, bb0.y, bb0.z, bb0.w, bb1.x, bb1.y, bb1.z, bb1.w};
#pragma unroll
      for (int i2 = 0; i2 < 8; i2++)
#pragma unroll
        for (int j2 = 0; j2 < 8; j2++)
          acc[i2][j2] = fmaf(av[i2], bv[j2], acc[i2][j2]);
    }
    __syncthreads();
  }
#pragma unroll
  for (int i2 = 0; i2 < 8; i2++) {
    int g = g0 + mg + i2;
    float bias = b_ih[g] + b_hh[g];
#pragma unroll
    for (int j2 = 0; j2 < 8; j2++) {
      C[(size_t)g * N + n0 + nn + j2] = acc[i2][j2] + bias;
    }
  }
}

// ---------------------------------------------------------------------------
// lstm_seq (R12): persistent kernel; UNCACHED h + master-aggregated barrier.
//
// R11 post-mortem: R10 (RMW chain) and R11 (flag sweep) both ~26 us/step ->
// the cost is what they SHARE: 2x threadfence_system per step (whole-L2
// wbl2+inv tag-walks, 32 blocks/XCD each) + 32K system-scope ops per sweep.
// R12 removes cache maintenance entirely:
//   * h stores: LDS-repacked to one aligned u64 per thread, stored with
//     system-scope (sc0+sc1, write-through). Nothing dirty in L2 -> no WB.
//   * h loads: system-scope u64 pairs (bypass L1+L2) -> no INV, remote-XCD
//     writes visible directly from L3. Costs ~8MB/XCD/step from L3 (~3-6us),
//     buys ~20us of fence removal.
//   * barrier: each block posts flags[bk]=gs+1 (256 posted stores); ONLY
//     block 0 sweeps flags (one lane per flag) and posts go=gs+1; all
//     other blocks poll the single go word with one lane. ~500 system ops
//     per step instead of 32K. Monotonic, skew<=1-safe with h ping-pong;
//     bounded spins (~1.7ms) -> fast-wrong-answer, never a hang.
// Ordering: __syncthreads() emits s_waitcnt vmcnt(0) for every wave ->
// uncached stores ACKed at the coherence point before t0 posts the flag;
// readers' next-step loads sit after the final s_barrier in program order.
//
// Tiling (R8-R11, correctness-proven): 256 blocks x 256 thr (4 waves,
// 1 block/CU forced by 128KB LDS -> latency hiding is ILP: unroll 8).
// Block bk: jblk=bk>>1 owns j=8*jblk..+7; bk&1 owns batch half. W in LDS
// staged once per chunk; c in registers.
// ---------------------------------------------------------------------------
__global__ __launch_bounds__(256)
void lstm_seq(const unsigned short* __restrict__ Whi,
              const unsigned short* __restrict__ Wlo,
              const float* __restrict__ XP, int N, int CT, int step0,
              unsigned short* __restrict__ h0hi, unsigned short* __restrict__ h0lo,
              unsigned short* __restrict__ h1hi, unsigned short* __restrict__ h1lo,
              float* __restrict__ cT, unsigned int* flags) {
  __shared__ bf16x8 Wlds[8192];                // 128 KB: hi (2 slabs) + lo
  __shared__ unsigned short hstage[64][2][8];  // 2 KB h-repack staging

  int bk = blockIdx.x;            // 0..255
  int jblk = bk >> 1;             // 0..127 -> j0 = 8*jblk
  int bh2 = bk & 1;               // batch half
  int t = threadIdx.x;            // 0..255
  int w = t >> 6;                 // wave 0..3
  int L = t & 63;
  int n = L & 15, q = L >> 4;
  int b = bh2 * 64 + w * 16 + n;
  int j0 = jblk * 8 + q;          // mt=0 row; mt=1 is j0+4

  // ---- stage BOTH W slabs (bk4 = 2*jblk, 2*jblk+1) into LDS once ----
  {
    float4* ldsf = (float4*)Wlds;
    const float4* s1 = (const float4*)(Whi + (size_t)jblk * 32768);
    const float4* s2 = (const float4*)(Wlo + (size_t)jblk * 32768);
#pragma unroll
    for (int i = 0; i < 16; i++) ldsf[t + 256 * i] = s1[t + 256 * i];
#pragma unroll
    for (int i = 0; i < 16; i++) ldsf[4096 + t + 256 * i] = s2[t + 256 * i];
  }

  int ci0 = j0 * BATCH + b;
  int ci1 = (j0 + 4) * BATCH + b;
  float cc0 = cT[ci0];            // c stays in registers for the whole chunk
  float cc1 = cT[ci1];

  size_t hoff = (size_t)b * HID + q * 8;

  // repack-store role for this thread: one u64 (4 shorts) per step
  int r_bl   = t >> 2;            // 0..63  batch-local
  int r_arr  = (t >> 1) & 1;      // 0=hi 1=lo
  int r_half = t & 1;             // low/high 4 j's of the 8-j group
  size_t r_off = (size_t)(bh2 * 64 + r_bl) * HID + jblk * 8 + r_half * 4;

  __syncthreads();

  for (int tt = 0; tt < CT; tt++) {
    int gs = step0 + tt;
    int odd = gs & 1;
    const unsigned short* Bh = (odd ? h1hi : h0hi) + hoff;
    const unsigned short* Bl = (odd ? h1lo : h0lo) + hoff;
    unsigned short* dhi = odd ? h0hi : h1hi;
    unsigned short* dlo = odd ? h0lo : h1lo;
    const float* xpc = XP + (size_t)tt * BATCH;

    // xp prefetch (independent of h) — overlaps the MFMA loop
    float xpv0[4], xpv1[4];
#pragma unroll
    for (int g = 0; g < 4; g++) {
      xpv0[g] = xpc[(size_t)(g * HID + j0) * N + b];
      xpv1[g] = xpc[(size_t)(g * HID + j0 + 4) * N + b];
    }

    f32x4 acc0 = {0.f, 0.f, 0.f, 0.f};
    f32x4 acc1 = {0.f, 0.f, 0.f, 0.f};
#pragma unroll 8
    for (int ks = 0; ks < 32; ks++) {
      bf16x8 bhv = ld_h16_uc(Bh + ks * 32);
      bf16x8 blv = ld_h16_uc(Bl + ks * 32);
      bf16x8 ah0 = Wlds[ks * 64 + L];
      bf16x8 ah1 = Wlds[2048 + ks * 64 + L];
      bf16x8 al0 = Wlds[4096 + ks * 64 + L];
      bf16x8 al1 = Wlds[6144 + ks * 64 + L];
      acc0 = __builtin_amdgcn_mfma_f32_16x16x32_bf16(ah0, bhv, acc0, 0, 0, 0);
      acc1 = __builtin_amdgcn_mfma_f32_16x16x32_bf16(ah1, bhv, acc1, 0, 0, 0);
      acc0 = __builtin_amdgcn_mfma_f32_16x16x32_bf16(ah0, blv, acc0, 0, 0, 0);
      acc1 = __builtin_amdgcn_mfma_f32_16x16x32_bf16(ah1, blv, acc1, 0, 0, 0);
      acc0 = __builtin_amdgcn_mfma_f32_16x16x32_bf16(al0, bhv, acc0, 0, 0, 0);
      acc1 = __builtin_amdgcn_mfma_f32_16x16x32_bf16(al1, bhv, acc1, 0, 0, 0);
    }

    {   // cell update, M-tile 0 (j = j0) -> LDS staging
      float i_ = 1.f / (1.f + expf(-(acc0[0] + xpv0[0])));
      float f_ = 1.f / (1.f + expf(-(acc0[1] + xpv0[1])));
      float g_ = tanhf(acc0[2] + xpv0[2]);
      float o_ = 1.f / (1.f + expf(-(acc0[3] + xpv0[3])));
      cc0 = f_ * cc0 + i_ * g_;
      float hn = o_ * tanhf(cc0);
      unsigned short hh = f2bf(hn);
      hstage[w * 16 + n][0][q] = hh;
      hstage[w * 16 + n][1][q] = f2bf(hn - bf2f(hh));
    }
    {   // cell update, M-tile 1 (j = j0+4) -> LDS staging
      float i_ = 1.f / (1.f + expf(-(acc1[0] + xpv1[0])));
      float f_ = 1.f / (1.f + expf(-(acc1[1] + xpv1[1])));
      float g_ = tanhf(acc1[2] + xpv1[2]);
      float o_ = 1.f / (1.f + expf(-(acc1[3] + xpv1[3])));
      cc1 = f_ * cc1 + i_ * g_;
      float hn = o_ * tanhf(cc1);
      unsigned short hh = f2bf(hn);
      hstage[w * 16 + n][0][q + 4] = hh;
      hstage[w * 16 + n][1][q + 4] = f2bf(hn - bf2f(hh));
    }

    __syncthreads();   // hstage filled

    {   // repack: one aligned u64 system-scope (write-through) store/thread
      unsigned long long v =
          *(const unsigned long long*)&hstage[r_bl][r_arr][r_half * 4];
      unsigned short* basep = r_arr ? dlo : dhi;
      __hip_atomic_store((unsigned long long*)(void*)(basep + r_off), v,
                         __ATOMIC_RELAXED, __HIP_MEMORY_SCOPE_SYSTEM);
    }

    // ---- master-aggregated device barrier (no cache maintenance) ----
    unsigned tgt = (unsigned)(gs + 1);
    __syncthreads();   // vmcnt(0) in every wave: all h stores globally visible
    if (t == 0)
      __hip_atomic_store(&flags[bk], tgt, __ATOMIC_RELAXED,
                         __HIP_MEMORY_SCOPE_SYSTEM);
    if (bk == 0) {
      unsigned gcnt = 0;   // each lane sweeps exactly one block's flag
      while (__hip_atomic_load(&flags[t], __ATOMIC_RELAXED,
                               __HIP_MEMORY_SCOPE_SYSTEM) < tgt &&
             ++gcnt < (1u << 16))
        __builtin_amdgcn_s_sleep(1);
      __syncthreads();
      if (t == 0)
        __hip_atomic_store(&flags[GO_IDX], tgt, __ATOMIC_RELAXED,
                           __HIP_MEMORY_SCOPE_SYSTEM);
    } else if (t == 0) {
      unsigned gcnt = 0;
      while (__hip_atomic_load(&flags[GO_IDX], __ATOMIC_RELAXED,
                               __HIP_MEMORY_SCOPE_SYSTEM) < tgt &&
             ++gcnt < (1u << 16))
        __builtin_amdgcn_s_sleep(1);
    }
    __syncthreads();   // all waves held until go observed; orders next loads
  }

  cT[ci0] = cc0;
  cT[ci1] = cc1;
}

// ---------------------------------------------------------------------------
// decode + softmax over batch dim (axis 0); h from hi+lo bf16 [B][H]
// ---------------------------------------------------------------------------
__global__ void decode_softmax(const unsigned short* __restrict__ hhi,
                               const unsigned short* __restrict__ hlo,
                               const float* __restrict__ Wd,
                               const float* __restrict__ bd, float* __restrict__ out) {
  __shared__ float lg[NOUT][BATCH];
  __shared__ float mx[NOUT], sm[NOUT];
  int t = threadIdx.x;  // 512 threads
  int b = t >> 2, o = t & 3;
  float s = bd[o];
  for (int j = 0; j < HID; j++) {
    float hv = bf2f(hhi[(size_t)b * HID + j]) + bf2f(hlo[(size_t)b * HID + j]);
    s += hv * Wd[o * HID + j];
  }
  lg[o][b] = s;
  __syncthreads();
  if (t < NOUT) {
    float m = -1e30f;
    for (int b2 = 0; b2 < BATCH; b2++) m = fmaxf(m, lg[t][b2]);
    float ss = 0.f;
    for (int b2 = 0; b2 < BATCH; b2++) ss += expf(lg[t][b2] - m);
    mx[t] = m; sm[t] = ss;
  }
  __syncthreads();
  out[b * NOUT + o] = expf(lg[o][b] - mx[o]) / sm[o];
}

// ---------------------------------------------------------------------------
extern "C" void kernel_launch(void* const* d_in, const int* in_sizes, int n_in,
                              void* d_out, int out_size, void* d_ws, size_t ws_size,
                              hipStream_t stream) {
  const float* inputs = (const float*)d_in[0];
  const float* h0     = (const float*)d_in[1];
  const float* c0     = (const float*)d_in[2];
  const float* W_ih   = (const float*)d_in[3];
  const float* W_hh   = (const float*)d_in[4];
  const float* b_ih   = (const float*)d_in[5];
  const float* b_hh   = (const float*)d_in[6];
  const float* W_dec  = (const float*)d_in[7];
  const float* b_dec  = (const float*)d_in[8];
  float* out = (float*)d_out;

  char* w = (char*)d_ws;
  unsigned short* Whi = (unsigned short*)w;  w += (size_t)G4 * HID * 2;
  unsigned short* Wlo = (unsigned short*)w;  w += (size_t)G4 * HID * 2;
  unsigned short* hhi[2], *hlo[2];
  hhi[0] = (unsigned short*)w;  w += (size_t)BATCH * HID * 2;
  hhi[1] = (unsigned short*)w;  w += (size_t)BATCH * HID * 2;
  hlo[0] = (unsigned short*)w;  w += (size_t)BATCH * HID * 2;
  hlo[1] = (unsigned short*)w;  w += (size_t)BATCH * HID * 2;
  float* cT = (float*)w;        w += (size_t)HID * BATCH * 4;
  unsigned int* flags = (unsigned int*)w;  w += 2048;   // 256 flags + go word
  size_t used = (size_t)(w - (char*)d_ws);

  // chunk size over timesteps, sized to fit ws (deterministic: ws_size const)
  size_t per_ct = ((size_t)INP * BATCH + (size_t)G4 * BATCH) * 4;  // Xt + XP per step
  int CT = 1;
  if (ws_size > used) {
    size_t avail = (ws_size - used) / per_ct;
    for (int c = SEQ; c >= 1; c >>= 1)
      if ((size_t)c <= avail) { CT = c; break; }
  }
  float* Xt = (float*)w;  w += (size_t)INP * BATCH * CT * 4;
  float* XP = (float*)w;
  int N = CT * BATCH;

  prepack_w<<<(256 * 32 * 64) / 256, 256, 0, stream>>>(W_hh, Whi, Wlo);
  init_state<<<BATCH * HID / 256, 256, 0, stream>>>(h0, c0, hhi[0], hlo[0], cT, flags);

  for (int t0 = 0; t0 < SEQ; t0 += CT) {
    transpose_in<<<dim3(N / 32, INP / 32), 256, 0, stream>>>(
        inputs + (size_t)t0 * BATCH * INP, Xt, N);
    gemm_xproj<<<dim3(G4 / 128, N / 128), 256, 0, stream>>>(
        W_ih, Xt, b_ih, b_hh, XP, N);

    int Nv = N, CTv = CT, step0 = t0;
    void* kargs[] = {
        (void*)&Whi, (void*)&Wlo, (void*)&XP, (void*)&Nv, (void*)&CTv,
        (void*)&step0, (void*)&hhi[0], (void*)&hlo[0], (void*)&hhi[1],
        (void*)&hlo[1], (void*)&cT, (void*)&flags};
    hipLaunchCooperativeKernel((const void*)lstm_seq, dim3(256), dim3(256),
                               kargs, 0, stream);
  }

  // SEQ even -> final h in buffer 0
  decode_softmax<<<1, 512, 0, stream>>>(hhi[0], hlo[0], W_dec, b_dec, out);
}

// Round 8
// 12496.112 us; speedup vs baseline: 3.7524x; 1.0004x over previous
//
#include <hip/hip_runtime.h>
#include <math.h>

#define SEQ   512
#define BATCH 128
#define INP   512
#define HID   1024
#define G4    4096   // 4*HID
#define NOUT  4

typedef short bf16x8 __attribute__((ext_vector_type(8)));
typedef float f32x4  __attribute__((ext_vector_type(4)));

__device__ __forceinline__ unsigned short f2bf(float x) {  // RNE fp32->bf16
  unsigned int u = __float_as_uint(x);
  unsigned int r = (u + 0x7FFFu + ((u >> 16) & 1u)) >> 16;
  return (unsigned short)r;
}
__device__ __forceinline__ float bf2f(unsigned short h) {
  return __uint_as_float(((unsigned int)h) << 16);
}

// uncached (system-scope, sc0+sc1) 16B load as 2x u64: bypasses L1+L2 so
// remote-XCD h writes are visible WITHOUT any cache-maintenance fences.
__device__ __forceinline__ bf16x8 ld_h16_uc(const unsigned short* p) {
  union { unsigned long long q[2]; bf16x8 v; } u;
  unsigned long long* pp = (unsigned long long*)(void*)p;
  u.q[0] = __hip_atomic_load(pp,     __ATOMIC_RELAXED, __HIP_MEMORY_SCOPE_SYSTEM);
  u.q[1] = __hip_atomic_load(pp + 1, __ATOMIC_RELAXED, __HIP_MEMORY_SCOPE_SYSTEM);
  return u.v;
}

// ---------------------------------------------------------------------------
// prepack W_hh [4096][1024] fp32 into fragment-linear bf16 hi/lo (proven):
// out index ((bk4*32 + kstep)*64 + L)*8 + i  holds W[row][k] with
//   m=L&15, q=L>>4, row=(m&3)*HID + bk4*4 + (m>>2), k=kstep*32+q*8+i.
// ---------------------------------------------------------------------------
__global__ void prepack_w(const float* __restrict__ W,
                          unsigned short* __restrict__ Whi,
                          unsigned short* __restrict__ Wlo) {
  int T = blockIdx.x * blockDim.x + threadIdx.x;   // < 256*32*64
  int L = T & 63;
  int kstep = (T >> 6) & 31;
  int bk = T >> 11;
  int m = L & 15, q = L >> 4;
  int row = (m & 3) * HID + bk * 4 + (m >> 2);
  int k = kstep * 32 + q * 8;
  const float* src = W + (size_t)row * HID + k;
  size_t o = (size_t)T * 8;
#pragma unroll
  for (int i = 0; i < 8; i++) {
    float x = src[i];
    unsigned short h = f2bf(x);
    Whi[o + i] = h;
    Wlo[o + i] = f2bf(x - bf2f(h));
  }
}

// ---------------------------------------------------------------------------
// init: h0 -> h_hi/h_lo bf16; c0 -> cT [H][B]; zero flag array (1024 uints).
// ---------------------------------------------------------------------------
__global__ void init_state(const float* __restrict__ h0, const float* __restrict__ c0,
                           unsigned short* __restrict__ hhi, unsigned short* __restrict__ hlo,
                           float* __restrict__ cT, unsigned int* __restrict__ flags) {
  int idx = blockIdx.x * blockDim.x + threadIdx.x;  // < BATCH*HID
  if (idx < 1024) flags[idx] = 0u;
  int b = idx >> 10;
  int j = idx & (HID - 1);
  float x = h0[idx];
  unsigned short h = f2bf(x);
  hhi[idx] = h;
  hlo[idx] = f2bf(x - bf2f(h));
  cT[j * BATCH + b] = c0[idx];
}

// ---------------------------------------------------------------------------
// transpose a chunk of inputs: in [nrows][INP] -> xt [INP][nrows]  (proven)
// ---------------------------------------------------------------------------
__global__ void transpose_in(const float* __restrict__ in, float* __restrict__ xt,
                             int nrows) {
  __shared__ float s[32][33];
  int tx = threadIdx.x & 31, ty = threadIdx.x >> 5;  // ty < 8
  int n0 = blockIdx.x * 32, i0 = blockIdx.y * 32;
#pragma unroll
  for (int r = 0; r < 4; r++) {
    int n = n0 + ty + 8 * r;
    s[ty + 8 * r][tx] = in[(size_t)n * INP + i0 + tx];
  }
  __syncthreads();
#pragma unroll
  for (int r = 0; r < 4; r++) {
    int i = i0 + ty + 8 * r;
    xt[(size_t)i * nrows + n0 + tx] = s[tx][ty + 8 * r];
  }
}

// ---------------------------------------------------------------------------
// gemm_xproj: C[4096][N] = W_ih[4096][512] @ Xt[512][N] + (b_ih + b_hh)
// PROVEN fp32 VALU kernel (xp must stay exact fp32 — R13 showed bf16 xp
// error is amplified ~100-300x by the 512-step recurrence).
// ---------------------------------------------------------------------------
__global__ __launch_bounds__(256, 3)
void gemm_xproj(const float* __restrict__ A, const float* __restrict__ Bm,
                const float* __restrict__ b_ih, const float* __restrict__ b_hh,
                float* __restrict__ C, int N) {
  __shared__ float As[32][128];
  __shared__ float Bs[32][128];
  int t = threadIdx.x;
  int g0 = blockIdx.x * 128;
  int n0 = blockIdx.y * 128;
  int mg = (t >> 4) * 8, nn = (t & 15) * 8;
  float acc[8][8] = {};
  for (int k0 = 0; k0 < INP; k0 += 32) {
#pragma unroll
    for (int r = 0; r < 4; r++) {
      int idx = t + 256 * r;
      int g = idx >> 3, i4 = idx & 7;
      float4 v = *(const float4*)&A[(size_t)(g0 + g) * INP + k0 + 4 * i4];
      As[4 * i4 + 0][g] = v.x; As[4 * i4 + 1][g] = v.y;
      As[4 * i4 + 2][g] = v.z; As[4 * i4 + 3][g] = v.w;
    }
#pragma unroll
    for (int r = 0; r < 4; r++) {
      int idx = t + 256 * r;
      int kk = idx >> 5, n4 = idx & 31;
      *(float4*)&Bs[kk][4 * n4] = *(const float4*)&Bm[(size_t)(k0 + kk) * N + n0 + 4 * n4];
    }
    __syncthreads();
#pragma unroll 4
    for (int kk = 0; kk < 32; kk++) {
      float4 a0 = *(const float4*)&As[kk][mg];
      float4 a1 = *(const float4*)&As[kk][mg + 4];
      float4 bb0 = *(const float4*)&Bs[kk][nn];
      float4 bb1 = *(const float4*)&Bs[kk][nn + 4];
      float av[8] = {a0.x, a0.y, a0.z, a0.w, a1.x, a1.y, a1.z, a1.w};
      float bv[8] = {bb0.x, bb0.y, bb0.z, bb0.w, bb1.x, bb1.y, bb1.z, bb1.w};
#pragma unroll
      for (int i2 = 0; i2 < 8; i2++)
#pragma unroll
        for (int j2 = 0; j2 < 8; j2++)
          acc[i2][j2] = fmaf(av[i2], bv[j2], acc[i2][j2]);
    }
    __syncthreads();
  }
#pragma unroll
  for (int i2 = 0; i2 < 8; i2++) {
    int g = g0 + mg + i2;
    float bias = b_ih[g] + b_hh[g];
#pragma unroll
    for (int j2 = 0; j2 < 8; j2++) {
      C[(size_t)g * N + n0 + nn + j2] = acc[i2][j2] + bias;
    }
  }
}

// ---------------------------------------------------------------------------
// lstm_seq (R15): EXACT R12 structure (the 12.5 ms passer) + three audited
// micro-deltas, each numerics-identical:
//   1. hstage padded [64][2][12] (was [..][8]): kills the 8-way LDS write
//      conflict (3.1M/chunk in R12). Same slots, u64 offsets 0/8/24/32 B.
//   2. go word replicated x8 (128 B apart): <=32 pollers/line (was 255 on
//      one line). Master stores 8 replicas after its sweep; protocol else
//      identical to R12's proven single-go.
//   3. next-step xp (cached, immutable XP) loaded BEFORE the barrier poll —
//      latency hides under the wait. Index clamped (no UB).
// The R13 2-deep register pipeline and MFMA-xproj are EXCLUDED (R13/R14
// failed; pipeline is the prime suspect and is quarantined).
// Interleaved load+MFMA loop, barrier fences, store path: byte-level R12.
// ---------------------------------------------------------------------------
__global__ __launch_bounds__(256)
void lstm_seq(const unsigned short* __restrict__ Whi,
              const unsigned short* __restrict__ Wlo,
              const float* __restrict__ XP, int N, int CT, int step0,
              unsigned short* __restrict__ h0hi, unsigned short* __restrict__ h0lo,
              unsigned short* __restrict__ h1hi, unsigned short* __restrict__ h1lo,
              float* __restrict__ cT, unsigned int* flags) {
  __shared__ bf16x8 Wlds[8192];                 // 128 KB: hi (2 slabs) + lo
  __shared__ unsigned short hstage[64][2][12];  // padded: conflict-free, 3 KB

  int bk = blockIdx.x;            // 0..255
  int jblk = bk >> 1;             // j0 = 8*jblk
  int bh2 = bk & 1;               // batch half
  int t = threadIdx.x;            // 0..255
  int w = t >> 6;                 // wave 0..3
  int L = t & 63;
  int n = L & 15, q = L >> 4;
  int b = bh2 * 64 + w * 16 + n;
  int j0 = jblk * 8 + q;          // mt=0 row; mt=1 is j0+4

  // ---- stage BOTH W slabs into LDS once per chunk ----
  {
    float4* ldsf = (float4*)Wlds;
    const float4* s1 = (const float4*)(Whi + (size_t)jblk * 32768);
    const float4* s2 = (const float4*)(Wlo + (size_t)jblk * 32768);
#pragma unroll
    for (int i = 0; i < 16; i++) ldsf[t + 256 * i] = s1[t + 256 * i];
#pragma unroll
    for (int i = 0; i < 16; i++) ldsf[4096 + t + 256 * i] = s2[t + 256 * i];
  }

  int ci0 = j0 * BATCH + b;
  int ci1 = (j0 + 4) * BATCH + b;
  float cc0 = cT[ci0];            // c in registers for the whole chunk
  float cc1 = cT[ci1];

  size_t hoff = (size_t)b * HID + q * 8;

  // repack-store role: one u64 (4 shorts) per step
  int r_bl   = t >> 2;            // 0..63 batch-local
  int r_arr  = (t >> 1) & 1;      // 0=hi 1=lo
  int r_half = t & 1;             // low/high 4 j's
  size_t r_off = (size_t)(bh2 * 64 + r_bl) * HID + jblk * 8 + r_half * 4;

  __syncthreads();

  // xp for tt=0 (cached loads; XP immutable during this kernel)
  float xa0[4], xa1[4];
#pragma unroll
  for (int g = 0; g < 4; g++) {
    xa0[g] = XP[(size_t)(g * HID + j0) * N + b];
    xa1[g] = XP[(size_t)(g * HID + j0 + 4) * N + b];
  }

  for (int tt = 0; tt < CT; tt++) {
    int gs = step0 + tt;
    int odd = gs & 1;
    const unsigned short* Bh = (odd ? h1hi : h0hi) + hoff;
    const unsigned short* Bl = (odd ? h1lo : h0lo) + hoff;
    unsigned short* dhi = odd ? h0hi : h1hi;
    unsigned short* dlo = odd ? h0lo : h1lo;

    f32x4 acc0 = {0.f, 0.f, 0.f, 0.f};
    f32x4 acc1 = {0.f, 0.f, 0.f, 0.f};
#pragma unroll 8
    for (int ks = 0; ks < 32; ks++) {
      bf16x8 bhv = ld_h16_uc(Bh + ks * 32);
      bf16x8 blv = ld_h16_uc(Bl + ks * 32);
      bf16x8 ah0 = Wlds[ks * 64 + L];
      bf16x8 ah1 = Wlds[2048 + ks * 64 + L];
      bf16x8 al0 = Wlds[4096 + ks * 64 + L];
      bf16x8 al1 = Wlds[6144 + ks * 64 + L];
      acc0 = __builtin_amdgcn_mfma_f32_16x16x32_bf16(ah0, bhv, acc0, 0, 0, 0);
      acc1 = __builtin_amdgcn_mfma_f32_16x16x32_bf16(ah1, bhv, acc1, 0, 0, 0);
      acc0 = __builtin_amdgcn_mfma_f32_16x16x32_bf16(ah0, blv, acc0, 0, 0, 0);
      acc1 = __builtin_amdgcn_mfma_f32_16x16x32_bf16(ah1, blv, acc1, 0, 0, 0);
      acc0 = __builtin_amdgcn_mfma_f32_16x16x32_bf16(al0, bhv, acc0, 0, 0, 0);
      acc1 = __builtin_amdgcn_mfma_f32_16x16x32_bf16(al1, bhv, acc1, 0, 0, 0);
    }

    {   // cell update, M-tile 0 (j = j0) -> LDS staging
      float i_ = 1.f / (1.f + expf(-(acc0[0] + xa0[0])));
      float f_ = 1.f / (1.f + expf(-(acc0[1] + xa0[1])));
      float g_ = tanhf(acc0[2] + xa0[2]);
      float o_ = 1.f / (1.f + expf(-(acc0[3] + xa0[3])));
      cc0 = f_ * cc0 + i_ * g_;
      float hn = o_ * tanhf(cc0);
      unsigned short hh = f2bf(hn);
      hstage[w * 16 + n][0][q] = hh;
      hstage[w * 16 + n][1][q] = f2bf(hn - bf2f(hh));
    }
    {   // cell update, M-tile 1 (j = j0+4) -> LDS staging
      float i_ = 1.f / (1.f + expf(-(acc1[0] + xa1[0])));
      float f_ = 1.f / (1.f + expf(-(acc1[1] + xa1[1])));
      float g_ = tanhf(acc1[2] + xa1[2]);
      float o_ = 1.f / (1.f + expf(-(acc1[3] + xa1[3])));
      cc1 = f_ * cc1 + i_ * g_;
      float hn = o_ * tanhf(cc1);
      unsigned short hh = f2bf(hn);
      hstage[w * 16 + n][0][q + 4] = hh;
      hstage[w * 16 + n][1][q + 4] = f2bf(hn - bf2f(hh));
    }

    __syncthreads();   // hstage filled

    {   // repack: one aligned u64 system-scope (write-through) store/thread
      unsigned long long v =
          *(const unsigned long long*)&hstage[r_bl][r_arr][r_half * 4];
      unsigned short* basep = r_arr ? dlo : dhi;
      __hip_atomic_store((unsigned long long*)(void*)(basep + r_off), v,
                         __ATOMIC_RELAXED, __HIP_MEMORY_SCOPE_SYSTEM);
    }

    // prefetch next step's xp (clamped index -> no UB); hides under barrier
    float xb0[4], xb1[4];
    {
      int tpf = (tt + 1 < CT) ? (tt + 1) : tt;
      const float* xpc = XP + (size_t)tpf * BATCH;
#pragma unroll
      for (int g = 0; g < 4; g++) {
        xb0[g] = xpc[(size_t)(g * HID + j0) * N + b];
        xb1[g] = xpc[(size_t)(g * HID + j0 + 4) * N + b];
      }
    }

    // ---- master-aggregated device barrier (no cache maintenance) ----
    unsigned tgt = (unsigned)(gs + 1);
    __syncthreads();   // vmcnt(0) in every wave: h stores globally visible
    if (t == 0)
      __hip_atomic_store(&flags[bk], tgt, __ATOMIC_RELAXED,
                         __HIP_MEMORY_SCOPE_SYSTEM);
    if (bk == 0) {
      unsigned gcnt = 0;   // each lane sweeps exactly one block's flag
      while (__hip_atomic_load(&flags[t], __ATOMIC_RELAXED,
                               __HIP_MEMORY_SCOPE_SYSTEM) < tgt &&
             ++gcnt < (1u << 16))
        __builtin_amdgcn_s_sleep(1);
      __syncthreads();
      if (t < 8)   // replicate go across 8 lines (128 B apart)
        __hip_atomic_store(&flags[512 + t * 32], tgt, __ATOMIC_RELAXED,
                           __HIP_MEMORY_SCOPE_SYSTEM);
    } else if (t == 0) {
      unsigned gcnt = 0;
      const unsigned int* gop = &flags[512 + (bk & 7) * 32];
      while (__hip_atomic_load(gop, __ATOMIC_RELAXED,
                               __HIP_MEMORY_SCOPE_SYSTEM) < tgt &&
             ++gcnt < (1u << 16))
        __builtin_amdgcn_s_sleep(1);
    }
    __syncthreads();   // all waves held until go observed

#pragma unroll
    for (int g = 0; g < 4; g++) { xa0[g] = xb0[g]; xa1[g] = xb1[g]; }
  }

  cT[ci0] = cc0;
  cT[ci1] = cc1;
}

// ---------------------------------------------------------------------------
// decode + softmax over batch dim (axis 0); h from hi+lo bf16 [B][H]
// ---------------------------------------------------------------------------
__global__ void decode_softmax(const unsigned short* __restrict__ hhi,
                               const unsigned short* __restrict__ hlo,
                               const float* __restrict__ Wd,
                               const float* __restrict__ bd, float* __restrict__ out) {
  __shared__ float lg[NOUT][BATCH];
  __shared__ float mx[NOUT], sm[NOUT];
  int t = threadIdx.x;  // 512 threads
  int b = t >> 2, o = t & 3;
  float s = bd[o];
  for (int j = 0; j < HID; j++) {
    float hv = bf2f(hhi[(size_t)b * HID + j]) + bf2f(hlo[(size_t)b * HID + j]);
    s += hv * Wd[o * HID + j];
  }
  lg[o][b] = s;
  __syncthreads();
  if (t < NOUT) {
    float m = -1e30f;
    for (int b2 = 0; b2 < BATCH; b2++) m = fmaxf(m, lg[t][b2]);
    float ss = 0.f;
    for (int b2 = 0; b2 < BATCH; b2++) ss += expf(lg[t][b2] - m);
    mx[t] = m; sm[t] = ss;
  }
  __syncthreads();
  out[b * NOUT + o] = expf(lg[o][b] - mx[o]) / sm[o];
}

// ---------------------------------------------------------------------------
extern "C" void kernel_launch(void* const* d_in, const int* in_sizes, int n_in,
                              void* d_out, int out_size, void* d_ws, size_t ws_size,
                              hipStream_t stream) {
  const float* inputs = (const float*)d_in[0];
  const float* h0     = (const float*)d_in[1];
  const float* c0     = (const float*)d_in[2];
  const float* W_ih   = (const float*)d_in[3];
  const float* W_hh   = (const float*)d_in[4];
  const float* b_ih   = (const float*)d_in[5];
  const float* b_hh   = (const float*)d_in[6];
  const float* W_dec  = (const float*)d_in[7];
  const float* b_dec  = (const float*)d_in[8];
  float* out = (float*)d_out;

  char* w = (char*)d_ws;
  unsigned short* Whi = (unsigned short*)w;  w += (size_t)G4 * HID * 2;
  unsigned short* Wlo = (unsigned short*)w;  w += (size_t)G4 * HID * 2;
  unsigned short* hhi[2], *hlo[2];
  hhi[0] = (unsigned short*)w;  w += (size_t)BATCH * HID * 2;
  hhi[1] = (unsigned short*)w;  w += (size_t)BATCH * HID * 2;
  hlo[0] = (unsigned short*)w;  w += (size_t)BATCH * HID * 2;
  hlo[1] = (unsigned short*)w;  w += (size_t)BATCH * HID * 2;
  float* cT = (float*)w;        w += (size_t)HID * BATCH * 4;
  unsigned int* flags = (unsigned int*)w;  w += 4096;   // 1024 uints
  size_t used = (size_t)(w - (char*)d_ws);

  // chunk size over timesteps, sized to fit ws (deterministic: ws_size const)
  size_t per_ct = ((size_t)INP * BATCH + (size_t)G4 * BATCH) * 4;  // Xt + XP per step
  int CT = 1;
  if (ws_size > used) {
    size_t avail = (ws_size - used) / per_ct;
    for (int c = SEQ; c >= 1; c >>= 1)
      if ((size_t)c <= avail) { CT = c; break; }
  }
  float* Xt = (float*)w;  w += (size_t)INP * BATCH * CT * 4;
  float* XP = (float*)w;
  int N = CT * BATCH;

  prepack_w<<<(256 * 32 * 64) / 256, 256, 0, stream>>>(W_hh, Whi, Wlo);
  init_state<<<BATCH * HID / 256, 256, 0, stream>>>(h0, c0, hhi[0], hlo[0], cT, flags);

  for (int t0 = 0; t0 < SEQ; t0 += CT) {
    transpose_in<<<dim3(N / 32, INP / 32), 256, 0, stream>>>(
        inputs + (size_t)t0 * BATCH * INP, Xt, N);
    gemm_xproj<<<dim3(G4 / 128, N / 128), 256, 0, stream>>>(
        W_ih, Xt, b_ih, b_hh, XP, N);

    int Nv = N, CTv = CT, step0 = t0;
    void* kargs[] = {
        (void*)&Whi, (void*)&Wlo, (void*)&XP, (void*)&Nv, (void*)&CTv,
        (void*)&step0, (void*)&hhi[0], (void*)&hlo[0], (void*)&hhi[1],
        (void*)&hlo[1], (void*)&cT, (void*)&flags};
    hipLaunchCooperativeKernel((const void*)lstm_seq, dim3(256), dim3(256),
                               kargs, 0, stream);
  }

  // SEQ even -> final h in buffer 0
  decode_softmax<<<1, 512, 0, stream>>>(hhi[0], hlo[0], W_dec, b_dec, out);
}